// Round 4
// baseline (530.232 us; speedup 1.0000x reference)
//
#include <hip/hip_runtime.h>
#include <cstdint>

#define B_   2
#define S_   4096
#define DM   1024
#define NH   8
#define HDIM 128
#define NWIN 15

typedef __attribute__((ext_vector_type(8))) short s8v;   // 8 bf16 (4 VGPRs)
typedef __attribute__((ext_vector_type(4))) float f4v;   // 4 fp32 acc

__device__ __forceinline__ float f_lo(unsigned int u){
  union { unsigned int i; float f; } v; v.i = u << 16; return v.f;
}
__device__ __forceinline__ float f_hi(unsigned int u){
  union { unsigned int i; float f; } v; v.i = u & 0xffff0000u; return v.f;
}
__device__ __forceinline__ unsigned short f2bf(float f){
  unsigned int x = __float_as_uint(f);
  x += 0x7fffu + ((x >> 16) & 1u);
  return (unsigned short)(x >> 16);
}
__device__ __forceinline__ unsigned int pack2(float a, float b){
  return (unsigned int)f2bf(a) | ((unsigned int)f2bf(b) << 16);
}

// ---------------------------------------------------------------------------
// Generic fp32 -> bf16 convert (8 elems/thread). Used for cw (2048 blocks)
// and x (4096 blocks).
// ---------------------------------------------------------------------------
__global__ __launch_bounds__(256) void k_cvtbf(const float* __restrict__ src,
                                               unsigned short* __restrict__ dst){
  size_t i = ((size_t)blockIdx.x*256 + threadIdx.x)*8;
  float4 a = *(const float4*)(src + i);
  float4 b = *(const float4*)(src + i + 4);
  uint4 r; r.x = pack2(a.x,a.y); r.y = pack2(a.z,a.w);
  r.z = pack2(b.x,b.y); r.w = pack2(b.z,b.w);
  *(uint4*)(dst + i) = r;
}

// ---------------------------------------------------------------------------
// fp32 transpose: x [b][s][1024] -> xT [b][1024][s].  64x64 tiles.
// ---------------------------------------------------------------------------
__global__ __launch_bounds__(256) void k_xposef(const float* __restrict__ x,
                                                float* __restrict__ xT){
  __shared__ float Ls[64][68];
  const int bid = blockIdx.x;             // b*1024 + st*16 + dt
  const int b = bid>>10, r = bid&1023, st = r>>4, dt = r&15;
  const int s0 = st*64, d0 = dt*64;
  const int tid = threadIdx.x;
#pragma unroll
  for(int p=0;p<4;p++){
    int rr = p*16 + (tid>>4), c4 = (tid&15)*4;
    *(float4*)&Ls[rr][c4] = *(const float4*)(x + ((size_t)(b*S_)+s0+rr)*DM + d0 + c4);
  }
  __syncthreads();
#pragma unroll
  for(int p=0;p<4;p++){
    int dr = p*16 + (tid>>4), c4 = (tid&15)*4;
    float4 v = { Ls[c4+0][dr], Ls[c4+1][dr], Ls[c4+2][dr], Ls[c4+3][dr] };
    *(float4*)(xT + ((size_t)(b*DM)+d0+dr)*S_ + s0 + c4) = v;
  }
}

// ---------------------------------------------------------------------------
// Diffusion in transposed space: block = (b, 2 d-rows), all I/O contiguous in s.
// cur kept in registers (LDS only for cross-thread neighbors).
// ---------------------------------------------------------------------------
__global__ __launch_bounds__(256) void k_diffuseT(const float* __restrict__ xT,
                                                  unsigned short* __restrict__ bcT){
  __shared__ float bufA[2][4096];
  __shared__ float bufB[2][4096];
  const int b  = blockIdx.x >> 9;
  const int d0 = (blockIdx.x & 511) * 2;
  const int tid = threadIdx.x;
  float cur[32], res[32];
#pragma unroll
  for(int k=0;k<32;k++){
    int e = tid + (k<<8); int ch = e>>12; int s = e&4095;
    float v = xT[((size_t)(b*DM)+d0+ch)*S_ + s];
    cur[k] = v; res[k] = 0.f; bufA[ch][s] = v;
  }
  __syncthreads();
#pragma unroll 1
  for(int st=0; st<12; st++){
    const int stride = 1<<st;
    float (*src)[4096] = (st&1) ? bufB : bufA;
    float (*dst)[4096] = (st&1) ? bufA : bufB;
#pragma unroll
    for(int k=0;k<32;k++){
      int e = tid + (k<<8); int ch=e>>12; int s=e&4095;
      float c = cur[k] + 0.5f*(src[ch][(s-stride)&4095] + src[ch][(s+stride)&4095]);
      dst[ch][s] = c; cur[k] = c; res[k] += c;
    }
    __syncthreads();
  }
#pragma unroll
  for(int k=0;k<32;k++){
    int e = tid + (k<<8); int ch=e>>12; int s=e&4095;
    bcT[((size_t)(b*DM)+d0+ch)*S_ + s] = f2bf(res[k]*(1.0f/13.0f));
  }
}

// ---------------------------------------------------------------------------
// bf16 transpose back: bcT [b][1024][s] -> bc [b][s][1024]. 64x64 tiles.
// ---------------------------------------------------------------------------
__global__ __launch_bounds__(256) void k_bcxpose(const unsigned short* __restrict__ bcT,
                                                 unsigned short* __restrict__ bc){
  __shared__ unsigned short Ls[64*72];
  const int bid = blockIdx.x;             // b*1024 + st*16 + dt
  const int b = bid>>10, r = bid&1023, st = r>>4, dt = r&15;
  const int s0 = st*64, d0 = dt*64;
  const int tid = threadIdx.x;
#pragma unroll
  for(int t=0;t<2;t++){
    int cl = tid + t*256; int dr = cl>>3, c = cl&7;
    *(uint4*)&Ls[dr*72 + c*8] = *(const uint4*)(bcT + ((size_t)(b*DM)+d0+dr)*S_ + s0 + c*8);
  }
  __syncthreads();
#pragma unroll
  for(int t=0;t<2;t++){
    int cl = tid + t*256; int sr = cl>>3, c = cl&7;
    unsigned short tmp[8];
#pragma unroll
    for(int j=0;j<8;j++) tmp[j] = Ls[(c*8+j)*72 + sr];
    *(uint4*)(bc + ((size_t)(b*S_)+s0+sr)*DM + d0 + c*8) = *(const uint4*)tmp;
  }
}

// ---------------------------------------------------------------------------
// Conv path (MFMA), unchanged.
// ---------------------------------------------------------------------------
__global__ __launch_bounds__(256) void k_xstage(const float* __restrict__ x,
                                                unsigned short* __restrict__ Asta){
  __shared__ float xs[4][1024];
  const int m = blockIdx.x;            // 0..127
  const int b = m>>6, t = m&63;
  const int tid = threadIdx.x;
  const float* xp = x + (size_t)(b*S_ + 4*t)*DM;
  for(int i=tid; i<4096; i+=256) xs[i>>10][i&1023] = xp[i];
  __syncthreads();
  float v[16];
#pragma unroll
  for(int e=0; e<16; e++) v[e] = xs[e&3][tid*4 + (e>>2)];
  uint4 r0, r1;
  r0.x = pack2(v[0],v[1]);  r0.y = pack2(v[2],v[3]);
  r0.z = pack2(v[4],v[5]);  r0.w = pack2(v[6],v[7]);
  r1.x = pack2(v[8],v[9]);  r1.y = pack2(v[10],v[11]);
  r1.z = pack2(v[12],v[13]); r1.w = pack2(v[14],v[15]);
  unsigned short* op = Asta + (size_t)m*4096 + tid*16;
  *(uint4*)op = r0;
  *(uint4*)(op+8) = r1;
}

__global__ __launch_bounds__(256) void k_gemmconv(const unsigned short* __restrict__ A,
                                                  const unsigned short* __restrict__ Bw,
                                                  float* __restrict__ part){
  __shared__ __align__(16) unsigned short As[128*64];
  __shared__ __align__(16) unsigned short Bs[128*64];
  const int nt = blockIdx.x, kt = blockIdx.y;
  const int n0 = nt<<7;
  const int tid = threadIdx.x, wid = tid>>6, lane = tid&63, quad = lane>>4, tl = lane&15;
  const int mq = (wid&1)*64, nq = (wid>>1)*64;
  f4v acc[4][4];
#pragma unroll
  for(int i=0;i<4;i++)
#pragma unroll
    for(int j=0;j<4;j++) acc[i][j] = (f4v)(0.f);

  for(int kc=kt*1024; kc<kt*1024+1024; kc+=64){
    __syncthreads();
#pragma unroll
    for(int t=0; t<4; t++){
      int cl = tid + t*256, m = cl>>3, c = cl&7;
      uint4 v = *(const uint4*)(A + (size_t)m*4096 + kc + c*8);
      *(uint4*)&As[m*64 + ((c ^ (m&7))<<3)] = v;
      uint4 w = *(const uint4*)(Bw + (size_t)(n0+m)*4096 + kc + c*8);
      *(uint4*)&Bs[m*64 + ((c ^ (m&7))<<3)] = w;
    }
    __syncthreads();
#pragma unroll
    for(int ks=0; ks<2; ks++){
      s8v af[4], bf[4];
#pragma unroll
      for(int i=0;i<4;i++){
        int ml = mq + i*16 + tl;
        af[i] = *(const s8v*)&As[ml*64 + (((ks*4+quad) ^ (ml&7))<<3)];
      }
#pragma unroll
      for(int j=0;j<4;j++){
        int nl = nq + j*16 + tl;
        bf[j] = *(const s8v*)&Bs[nl*64 + (((ks*4+quad) ^ (nl&7))<<3)];
      }
#pragma unroll
      for(int i=0;i<4;i++)
#pragma unroll
        for(int j=0;j<4;j++)
          acc[i][j] = __builtin_amdgcn_mfma_f32_16x16x32_bf16(af[i], bf[j], acc[i][j], 0, 0, 0);
    }
  }
  float* pp = part + (size_t)kt*131072;
#pragma unroll
  for(int i=0;i<4;i++)
#pragma unroll
    for(int r=0;r<4;r++){
      int m = mq + i*16 + quad*4 + r;
#pragma unroll
      for(int j=0;j<4;j++){
        int n = n0 + nq + j*16 + tl;
        pp[m*1024 + n] = acc[i][j][r];
      }
    }
}

__global__ __launch_bounds__(256) void k_convred(const float* __restrict__ part,
                                                 const float* __restrict__ cb,
                                                 unsigned short* __restrict__ kv){
  int i = blockIdx.x*256 + threadIdx.x;   // 131072
  int m = i>>10, o = i&1023;
  float v = part[i] + part[131072+i] + part[262144+i] + part[393216+i] + cb[o];
  int b = m>>6, t = m&63, h = o>>7, hd = o&127;
  kv[((size_t)(b*NH + h)*128 + t)*HDIM + hd] = f2bf(v);
}

__global__ __launch_bounds__(256) void k_gmem(const float* __restrict__ g,
                                              unsigned short* __restrict__ kv){
  int i = blockIdx.x*256 + threadIdx.x;   // 131072 total
  int hd = i & 127, gt = (i>>7)&63, h = (i>>13)&7, b = i>>16;
  kv[((size_t)(b*NH + h)*128 + 64 + gt)*HDIM + hd] = f2bf(g[((size_t)(h*64 + gt))*HDIM + hd]);
}

// ---------------------------------------------------------------------------
// MFMA flash attention, bf16 inputs.
// R9 (counters R8: Occupancy 22%, MfmaUtil 17%, ~48% no-issue, 3 blk/CU and
// MODE0 grid 960 > capacity 768 -> dispatch tail):
//  - P buffer OVERLAYS the K-tile region. K is only read by QK^T; P is only
//    written after QK reads finish. One extra barrier (placed AFTER the
//    softmax VALU, so its wait hides behind exp2 work) makes it safe.
//    LDS 51.2 -> 34.8 KB => 4 blocks/CU, 16 waves/CU, grid 960 fully
//    resident (capacity 1024), zero tail.  Epilogue 128x136 = same 34816 B.
//  - s_setprio(1) around MFMA clusters (T5): 4 independent blocks/CU at
//    different phases -> scheduler has roles to arbitrate.
// VGPR 84 <= 128 cap @ launch_bounds(256,4) -> no spill (R7 lesson: checked).
// ---------------------------------------------------------------------------
template<int MODE>
__global__ __launch_bounds__(256, 4) void k_attn(const unsigned short* __restrict__ xb,
                                                 const unsigned short* __restrict__ kvb,
                                                 unsigned short* __restrict__ outb){
  __shared__ __align__(16) unsigned short sh[17408];  // 34.8 KB
  constexpr int KSo = 0;      // K-tile [64][128] swizzled  (16 KB)
  constexpr int PSo = 0;      // P [128][64] swizzled — overlays K (safe: bar3)
  constexpr int VTo = 8192;   // V^T [128][72]              (18 KB)

  const int b = blockIdx.y;
  int h, n, qt, nkt;
  if(MODE==0){
    int r = blockIdx.x;                  // 480 = 15n * 8h * 4qt
    int s = (r&7)*60 + (r>>3);           // bijective chunked XCD swizzle
    qt = s&3; h = (s>>2)&7; n = s>>5; nkt = 8;
  } else {
    int r = blockIdx.x; h = r>>5; qt = r&31; n = 0; nkt = 2;
  }

  const int tid  = threadIdx.x;
  const int wid  = tid>>6, lane = tid&63, quad = lane>>4, tl = lane&15;
  const int sQ   = (MODE==0) ? (n*256 + qt*128) : (qt*128);

  // Q fragments (held in registers for all kt)
  s8v qf[2][4];
#pragma unroll
  for(int qi=0; qi<2; qi++){
    int qr = sQ + wid*32 + qi*16 + tl;
    const unsigned short* qp = xb + ((size_t)(b*S_) + qr)*DM + h*HDIM;
#pragma unroll
    for(int ks=0; ks<4; ks++)
      qf[qi][ks] = *(const s8v*)(qp + ks*32 + quad*8);
  }

  const unsigned short* kbase = (MODE==0)
      ? xb + ((size_t)(b*S_) + n*256)*DM + h*HDIM
      : kvb + (size_t)(b*NH+h)*128*HDIM;
  const int kstride = (MODE==0) ? DM : HDIM;
  const int mrow = (tid&15)*4;     // base t-row of this thread's 4 rows
  const int cg   = tid>>4;         // hd granule (8 ushorts), 0..15

  // prologue: prefetch tile 0 into registers
  uint4 rg[4];
#pragma unroll
  for(int j=0;j<4;j++)
    rg[j] = *(const uint4*)(kbase + (size_t)(mrow+j)*kstride + cg*8);

  f4v oacc[8][2];
#pragma unroll
  for(int ht=0; ht<8; ht++){ oacc[ht][0] = (f4v)(0.f); oacc[ht][1] = (f4v)(0.f); }
  float l_[2] = {0.f, 0.f};

  const float SC2 = 0.12751743f;   // (1/sqrt(128)) * log2(e)

  for(int kt=0; kt<nkt; kt++){
    __syncthreads();               // prev PV done reading P(=K region) and VT
    // --- stage K tile (swizzled) from regs: 4 conflict-free uint4 writes
#pragma unroll
    for(int j=0;j<4;j++){
      int t = mrow + j;
      *(uint4*)&sh[KSo + t*128 + ((cg ^ (t&7))<<3)] = rg[j];
    }
    // --- stage V^T from regs: pack 4 consecutive t per hd, ds_write_b64
    {
      const unsigned int* w0 = (const unsigned int*)&rg[0];
      const unsigned int* w1 = (const unsigned int*)&rg[1];
      const unsigned int* w2 = (const unsigned int*)&rg[2];
      const unsigned int* w3 = (const unsigned int*)&rg[3];
#pragma unroll
      for(int i=0;i<8;i++){
        int w = i>>1;
        unsigned int a, c2;
        if(i&1){ a  = (w0[w]>>16) | (w1[w] & 0xffff0000u);
                 c2 = (w2[w]>>16) | (w3[w] & 0xffff0000u); }
        else   { a  = (w0[w] & 0xffffu) | (w1[w]<<16);
                 c2 = (w2[w] & 0xffffu) | (w3[w]<<16); }
        uint2 u = {a, c2};
        *(uint2*)&sh[VTo + (cg*8+i)*72 + mrow] = u;
      }
    }
    __syncthreads();               // staging visible
    // --- prefetch next K tile into regs (latency hides under compute)
    if(kt+1 < nkt){
      const unsigned short* np = kbase + (size_t)((kt+1)*64 + mrow)*kstride + cg*8;
#pragma unroll
      for(int j=0;j<4;j++) rg[j] = *(const uint4*)(np + (size_t)j*kstride);
    }

    // --- S^T[t][q] = K.Q^T (raw scores, scale folded into exp2)
    f4v st[4][2];
    __builtin_amdgcn_s_setprio(1);
#pragma unroll
    for(int tt=0; tt<4; tt++){
      st[tt][0] = (f4v)(0.f); st[tt][1] = (f4v)(0.f);
      int row = tt*16 + tl;
#pragma unroll
      for(int ks=0; ks<4; ks++){
        s8v af = *(const s8v*)&sh[KSo + row*128 + (((ks*4+quad) ^ (row&7))<<3)];
        st[tt][0] = __builtin_amdgcn_mfma_f32_16x16x32_bf16(af, qf[0][ks], st[tt][0], 0, 0, 0);
        st[tt][1] = __builtin_amdgcn_mfma_f32_16x16x32_bf16(af, qf[1][ks], st[tt][1], 0, 0, 0);
      }
    }
    __builtin_amdgcn_s_setprio(0);

    // --- softmax, no max subtraction (scores bounded; exp2 arg <= ~27)
#pragma unroll
    for(int qi=0; qi<2; qi++){
      float ps = 0.f;
#pragma unroll
      for(int tt=0; tt<4; tt++)
#pragma unroll
        for(int r=0; r<4; r++){
          float p = exp2f(st[tt][qi][r]*SC2);
          st[tt][qi][r] = p; ps += p;
        }
      ps += __shfl_xor(ps, 16);
      ps += __shfl_xor(ps, 32);
      l_[qi] += ps;
    }

    __syncthreads();               // all waves' QK reads of K done -> P may overlay

    // --- P store: [128][64] XOR-swizzled (granule-8), floor-rate
#pragma unroll
    for(int qi=0; qi<2; qi++){
      int ql = wid*32 + qi*16 + tl;
#pragma unroll
      for(int tt=0; tt<4; tt++){
        ushort4 u = { f2bf(st[tt][qi][0]), f2bf(st[tt][qi][1]),
                      f2bf(st[tt][qi][2]), f2bf(st[tt][qi][3]) };
        *(ushort4*)&sh[PSo + ql*64 + (((tt*2 + (quad>>1)) ^ (ql&7))<<3) + (quad&1)*4] = u;
      }
    }

    // --- O^T += V^T . P^T  (P rows are wave-private: no barrier needed)
    __builtin_amdgcn_s_setprio(1);
#pragma unroll
    for(int kk=0; kk<2; kk++){
      int ql0 = wid*32 + tl, ql1 = wid*32 + 16 + tl;
      s8v pb0 = *(const s8v*)&sh[PSo + ql0*64 + (((kk*4+quad) ^ (ql0&7))<<3)];
      s8v pb1 = *(const s8v*)&sh[PSo + ql1*64 + (((kk*4+quad) ^ (ql1&7))<<3)];
#pragma unroll
      for(int ht=0; ht<8; ht++){
        s8v vf = *(const s8v*)&sh[VTo + (ht*16 + tl)*72 + kk*32 + quad*8];
        oacc[ht][0] = __builtin_amdgcn_mfma_f32_16x16x32_bf16(vf, pb0, oacc[ht][0], 0, 0, 0);
        oacc[ht][1] = __builtin_amdgcn_mfma_f32_16x16x32_bf16(vf, pb1, oacc[ht][1], 0, 0, 0);
      }
    }
    __builtin_amdgcn_s_setprio(0);
  }

  // normalize and write out via LDS transpose (overlays everything, stride 136)
#pragma unroll
  for(int qi=0; qi<2; qi++){
    float inv = 1.0f/l_[qi];
#pragma unroll
    for(int ht=0; ht<8; ht++) oacc[ht][qi] *= inv;
  }
  __syncthreads();
#pragma unroll
  for(int qi=0; qi<2; qi++){
    int ql = wid*32 + qi*16 + tl;
#pragma unroll
    for(int ht=0; ht<8; ht++){
      ushort4 u = { f2bf(oacc[ht][qi][0]), f2bf(oacc[ht][qi][1]),
                    f2bf(oacc[ht][qi][2]), f2bf(oacc[ht][qi][3]) };
      *(ushort4*)&sh[ql*136 + ht*16 + quad*4] = u;
    }
  }
  __syncthreads();
  {
    int ql = tid>>1, half = tid&1;
    size_t row = (MODE==0) ? (size_t)((b*NWIN + n)*512 + qt*128 + ql)
                           : (size_t)(b*S_ + qt*128 + ql);
    unsigned short* op = outb + row*DM + h*HDIM + half*64;
#pragma unroll
    for(int c=0; c<8; c++){
      uint4 v = *(const uint4*)&sh[ql*136 + half*64 + c*8];
      *(uint4*)(op + c*8) = v;
    }
  }
}

// ---------------------------------------------------------------------------
// Triangular-weighted overlap-add
// ---------------------------------------------------------------------------
__global__ __launch_bounds__(256) void k_combine(const unsigned short* __restrict__ wso,
                                                 unsigned short* __restrict__ loc){
  const int bid = blockIdx.x;          // B*S
  const int b = bid >> 12, s = bid & 4095;
  const int tid = threadIdx.x;
  const int nhi = s >> 8, sl = s & 255;
  const int c0 = tid*4;
  float n0=0.f, n1=0.f, n2=0.f, n3=0.f, den=0.f;
  if(nhi <= 14){
    float tr = 0.5f + (float)sl*(1.0f/511.0f);
    den += tr;
    uint2 u = *(const uint2*)(wso + (size_t)((b*NWIN + nhi)*512 + sl)*DM + c0);
    n0 += tr*f_lo(u.x); n1 += tr*f_hi(u.x); n2 += tr*f_lo(u.y); n3 += tr*f_hi(u.y);
  }
  if(nhi >= 1){
    int q2 = sl + 256;
    float tr = 0.5f + (float)q2*(1.0f/511.0f);
    den += tr;
    uint2 u = *(const uint2*)(wso + (size_t)((b*NWIN + nhi-1)*512 + q2)*DM + c0);
    n0 += tr*f_lo(u.x); n1 += tr*f_hi(u.x); n2 += tr*f_lo(u.y); n3 += tr*f_hi(u.y);
  }
  float di = 1.0f/den;
  uint2 o; o.x = pack2(n0*di, n1*di); o.y = pack2(n2*di, n3*di);
  *(uint2*)(loc + (size_t)(b*S_ + s)*DM + c0) = o;
}

// ---------------------------------------------------------------------------
// Weight transpose+convert: W [K][1024] fp32 -> WT [1024][K] bf16 (64x64 tiles)
// ---------------------------------------------------------------------------
__global__ __launch_bounds__(256) void k_wcvt(const float* __restrict__ W,
                                              unsigned short* __restrict__ WT, int K){
  __shared__ float Ls[64][68];
  int kt = blockIdx.x >> 4, nt = blockIdx.x & 15;
  int k0 = kt<<6, n0 = nt<<6;
  int tid = threadIdx.x;
#pragma unroll
  for(int p=0; p<4; p++){
    int r = p*16 + (tid>>4), c4 = (tid&15)*4;
    float4 v = *(const float4*)(W + (size_t)(k0+r)*1024 + n0 + c4);
    *(float4*)&Ls[r][c4] = v;
  }
  __syncthreads();
  int nn = tid>>2, kq = tid&3;
#pragma unroll
  for(int c=0; c<4; c++){
    int k = kq*16 + c*4;
    ushort4 u = { f2bf(Ls[k+0][nn]), f2bf(Ls[k+1][nn]), f2bf(Ls[k+2][nn]), f2bf(Ls[k+3][nn]) };
    *(ushort4*)(WT + (size_t)(n0+nn)*K + k0 + k) = u;
  }
}

// ---------------------------------------------------------------------------
// MFMA GEMM 128x128 tile, BK=64, XOR-swizzled LDS, 4 waves x (64x64 quadrant).
// MODE 0: + sigmoid gate mix epilogue -> mixed (bf16).  MODE 1: + bias -> out fp32.
// ---------------------------------------------------------------------------
template<int MODE>
__global__ __launch_bounds__(256) void k_gemm2(const unsigned short* __restrict__ A0,
                                               const unsigned short* __restrict__ A1,
                                               const unsigned short* __restrict__ WT,
                                               const float* __restrict__ bias,
                                               const unsigned short* __restrict__ loc,
                                               const unsigned short* __restrict__ glo,
                                               const unsigned short* __restrict__ bcb,
                                               unsigned short* __restrict__ outb,
                                               float* __restrict__ outf){
  const int KTOT = (MODE==0) ? 2048 : 1024;
  __shared__ __align__(16) unsigned short As[128*64];
  __shared__ __align__(16) unsigned short Bs[128*64];
  const int mt = blockIdx.x >> 3, nt = blockIdx.x & 7;
  const int m0 = mt<<7, n0 = nt<<7;
  const int tid = threadIdx.x, wid = tid>>6, lane = tid&63, quad = lane>>4, tl = lane&15;
  const int mq = (wid&1)*64, nq = (wid>>1)*64;
  f4v acc[4][4];
#pragma unroll
  for(int i=0;i<4;i++)
#pragma unroll
    for(int j=0;j<4;j++) acc[i][j] = (f4v)(0.f);

  for(int kc=0; kc<KTOT; kc+=64){
    __syncthreads();
    const unsigned short* Ab = (MODE==0 && kc>=1024) ? A1 : A0;
    const int kb = (MODE==0) ? (kc & 1023) : kc;
#pragma unroll
    for(int t=0; t<4; t++){
      int cl = tid + t*256, m = cl>>3, c = cl&7;
      uint4 v = *(const uint4*)(Ab + (size_t)(m0+m)*1024 + kb + c*8);
      *(uint4*)&As[m*64 + ((c ^ (m&7))<<3)] = v;
      uint4 w = *(const uint4*)(WT + (size_t)(n0+m)*KTOT + kc + c*8);
      *(uint4*)&Bs[m*64 + ((c ^ (m&7))<<3)] = w;
    }
    __syncthreads();
#pragma unroll
    for(int ks=0; ks<2; ks++){
      s8v af[4], bf[4];
#pragma unroll
      for(int i=0;i<4;i++){
        int ml = mq + i*16 + tl;
        af[i] = *(const s8v*)&As[ml*64 + (((ks*4+quad) ^ (ml&7))<<3)];
      }
#pragma unroll
      for(int j=0;j<4;j++){
        int nl = nq + j*16 + tl;
        bf[j] = *(const s8v*)&Bs[nl*64 + (((ks*4+quad) ^ (nl&7))<<3)];
      }
#pragma unroll
      for(int i=0;i<4;i++)
#pragma unroll
        for(int j=0;j<4;j++)
          acc[i][j] = __builtin_amdgcn_mfma_f32_16x16x32_bf16(af[i], bf[j], acc[i][j], 0, 0, 0);
    }
  }

#pragma unroll
  for(int i=0;i<4;i++){
#pragma unroll
    for(int r=0;r<4;r++){
      int m = m0 + mq + i*16 + quad*4 + r;
      size_t rowb = (size_t)m * 1024;
#pragma unroll
      for(int j=0;j<4;j++){
        int nn = n0 + nq + j*16 + tl;
        float v = acc[i][j][r] + bias[nn];
        if(MODE==0){
          float g  = 1.0f/(1.0f + __expf(-v));
          float lv = f_lo((unsigned int)loc[rowb+nn]);
          float gv = f_lo((unsigned int)glo[rowb+nn]);
          float bv = f_lo((unsigned int)bcb[rowb+nn]);
          outb[rowb+nn] = f2bf(g*lv + (1.0f-g)*gv + bv);
        } else {
          outf[rowb+nn] = v;
        }
      }
    }
  }
}

extern "C" void kernel_launch(void* const* d_in, const int* in_sizes, int n_in,
                              void* d_out, int out_size, void* d_ws, size_t ws_size,
                              hipStream_t stream){
  const float* x  = (const float*)d_in[0];
  const float* gm = (const float*)d_in[1];
  const float* cw = (const float*)d_in[2];
  const float* cb = (const float*)d_in[3];
  const float* mw = (const float*)d_in[4];
  const float* mb = (const float*)d_in[5];
  const float* ow = (const float*)d_in[6];
  const float* ob = (const float*)d_in[7];
  float* out = (float*)d_out;

  char* ws = (char*)d_ws;
  const size_t SZ = (size_t)B_*S_*DM*2;                 // 16.78 MB per bf16 field
  unsigned short* localb = (unsigned short*)(ws);
  unsigned short* globb  = (unsigned short*)(ws + SZ);
  unsigned short* bcb    = (unsigned short*)(ws + 2*SZ);
  unsigned short* kvb    = (unsigned short*)(ws + 3*SZ);
  unsigned short* wso    = (unsigned short*)(ws + 3*SZ + 524288);
  unsigned short* mixed  = wso;                          // first 16.78 MB of wso region
  unsigned short* wt1    = (unsigned short*)(ws + 3*SZ + 524288 + SZ);            // 4 MB
  unsigned short* wt2    = (unsigned short*)(ws + 3*SZ + 524288 + SZ + 4194304);  // 2 MB
  // conv-path scratch overlays localb region (consumed before k_xbf)
  unsigned short* cwb    = (unsigned short*)(ws);               // 8 MB bf16 [1024][4096]
  unsigned short* asta   = (unsigned short*)(ws + 8388608);     // 1 MB bf16 [128][4096]
  float*          cpart  = (float*)        (ws + 9437184);      // 2 MB fp32 [4][128][1024]
  // overlays: xT over globb+bcb (dead until attn<1>/bcxpose); bcT over wso
  float*          xT     = (float*)(ws + SZ);                   // 33.5 MB fp32 [b][1024][4096]
  unsigned short* bcT    = wso;                                 // 16.78 MB bf16 [b][1024][4096]
  unsigned short* xbf    = (unsigned short*)(ws);               // 16.78 MB bf16 x (over conv scratch)

  // conv path (uses ws[0..11.5M])
  k_cvtbf   <<<2048, 256, 0, stream>>>(cw, cwb);
  k_xstage  <<<128,  256, 0, stream>>>(x, asta);
  k_gemmconv<<<dim3(8,4), 256, 0, stream>>>(asta, cwb, cpart);
  k_convred <<<512,  256, 0, stream>>>(cpart, cb, kvb);
  k_gmem    <<<512,  256, 0, stream>>>(gm, kvb);
  // diffusion path (transposed space)
  k_xposef  <<<2048, 256, 0, stream>>>(x, xT);
  k_diffuseT<<<1024, 256, 0, stream>>>(xT, bcT);
  k_bcxpose <<<2048, 256, 0, stream>>>(bcT, bcb);
  // bf16 x for attention (overwrites conv scratch)
  k_cvtbf   <<<4096, 256, 0, stream>>>(x, xbf);
  k_attn<1> <<<dim3(256,2), 256, 0, stream>>>(xbf, kvb, globb);
  k_attn<0> <<<dim3(480,2), 256, 0, stream>>>(xbf, kvb, wso);   // overwrites bcT (dead)
  k_combine <<<8192, 256, 0, stream>>>(wso, localb);            // overwrites xbf (dead)
  k_wcvt    <<<512,  256, 0, stream>>>(mw, wt1, 2048);
  k_wcvt    <<<256,  256, 0, stream>>>(ow, wt2, 1024);
  k_gemm2<0><<<512, 256, 0, stream>>>(localb, globb, wt1, mb, localb, globb, bcb, mixed, nullptr);
  k_gemm2<1><<<512, 256, 0, stream>>>(mixed, nullptr, wt2, ob, nullptr, nullptr, nullptr, nullptr, out);
}

// Round 5
// 389.433 us; speedup vs baseline: 1.3615x; 1.3615x over previous
//
#include <hip/hip_runtime.h>
#include <cstdint>

#define B_   2
#define S_   4096
#define DM   1024
#define NH   8
#define HDIM 128
#define NWIN 15

typedef __attribute__((ext_vector_type(8))) short s8v;   // 8 bf16 (4 VGPRs)
typedef __attribute__((ext_vector_type(4))) float f4v;   // 4 fp32 acc

__device__ __forceinline__ float f_lo(unsigned int u){
  union { unsigned int i; float f; } v; v.i = u << 16; return v.f;
}
__device__ __forceinline__ float f_hi(unsigned int u){
  union { unsigned int i; float f; } v; v.i = u & 0xffff0000u; return v.f;
}
__device__ __forceinline__ unsigned short f2bf(float f){
  unsigned int x = __float_as_uint(f);
  x += 0x7fffu + ((x >> 16) & 1u);
  return (unsigned short)(x >> 16);
}
__device__ __forceinline__ unsigned int pack2(float a, float b){
  return (unsigned int)f2bf(a) | ((unsigned int)f2bf(b) << 16);
}

// ---------------------------------------------------------------------------
// Generic fp32 -> bf16 convert (8 elems/thread). Used for cw (2048 blocks)
// and x (4096 blocks).
// ---------------------------------------------------------------------------
__global__ __launch_bounds__(256) void k_cvtbf(const float* __restrict__ src,
                                               unsigned short* __restrict__ dst){
  size_t i = ((size_t)blockIdx.x*256 + threadIdx.x)*8;
  float4 a = *(const float4*)(src + i);
  float4 b = *(const float4*)(src + i + 4);
  uint4 r; r.x = pack2(a.x,a.y); r.y = pack2(a.z,a.w);
  r.z = pack2(b.x,b.y); r.w = pack2(b.z,b.w);
  *(uint4*)(dst + i) = r;
}

// ---------------------------------------------------------------------------
// fp32 transpose: x [b][s][1024] -> xT [b][1024][s].  64x64 tiles.
// ---------------------------------------------------------------------------
__global__ __launch_bounds__(256) void k_xposef(const float* __restrict__ x,
                                                float* __restrict__ xT){
  __shared__ float Ls[64][68];
  const int bid = blockIdx.x;             // b*1024 + st*16 + dt
  const int b = bid>>10, r = bid&1023, st = r>>4, dt = r&15;
  const int s0 = st*64, d0 = dt*64;
  const int tid = threadIdx.x;
#pragma unroll
  for(int p=0;p<4;p++){
    int rr = p*16 + (tid>>4), c4 = (tid&15)*4;
    *(float4*)&Ls[rr][c4] = *(const float4*)(x + ((size_t)(b*S_)+s0+rr)*DM + d0 + c4);
  }
  __syncthreads();
#pragma unroll
  for(int p=0;p<4;p++){
    int dr = p*16 + (tid>>4), c4 = (tid&15)*4;
    float4 v = { Ls[c4+0][dr], Ls[c4+1][dr], Ls[c4+2][dr], Ls[c4+3][dr] };
    *(float4*)(xT + ((size_t)(b*DM)+d0+dr)*S_ + s0 + c4) = v;
  }
}

// ---------------------------------------------------------------------------
// Diffusion in transposed space: block = (b, 2 d-rows), all I/O contiguous in s.
// cur kept in registers (LDS only for cross-thread neighbors).
// ---------------------------------------------------------------------------
__global__ __launch_bounds__(256) void k_diffuseT(const float* __restrict__ xT,
                                                  unsigned short* __restrict__ bcT){
  __shared__ float bufA[2][4096];
  __shared__ float bufB[2][4096];
  const int b  = blockIdx.x >> 9;
  const int d0 = (blockIdx.x & 511) * 2;
  const int tid = threadIdx.x;
  float cur[32], res[32];
#pragma unroll
  for(int k=0;k<32;k++){
    int e = tid + (k<<8); int ch = e>>12; int s = e&4095;
    float v = xT[((size_t)(b*DM)+d0+ch)*S_ + s];
    cur[k] = v; res[k] = 0.f; bufA[ch][s] = v;
  }
  __syncthreads();
#pragma unroll 1
  for(int st=0; st<12; st++){
    const int stride = 1<<st;
    float (*src)[4096] = (st&1) ? bufB : bufA;
    float (*dst)[4096] = (st&1) ? bufA : bufB;
#pragma unroll
    for(int k=0;k<32;k++){
      int e = tid + (k<<8); int ch=e>>12; int s=e&4095;
      float c = cur[k] + 0.5f*(src[ch][(s-stride)&4095] + src[ch][(s+stride)&4095]);
      dst[ch][s] = c; cur[k] = c; res[k] += c;
    }
    __syncthreads();
  }
#pragma unroll
  for(int k=0;k<32;k++){
    int e = tid + (k<<8); int ch=e>>12; int s=e&4095;
    bcT[((size_t)(b*DM)+d0+ch)*S_ + s] = f2bf(res[k]*(1.0f/13.0f));
  }
}

// ---------------------------------------------------------------------------
// bf16 transpose back: bcT [b][1024][s] -> bc [b][s][1024]. 64x64 tiles.
// ---------------------------------------------------------------------------
__global__ __launch_bounds__(256) void k_bcxpose(const unsigned short* __restrict__ bcT,
                                                 unsigned short* __restrict__ bc){
  __shared__ unsigned short Ls[64*72];
  const int bid = blockIdx.x;             // b*1024 + st*16 + dt
  const int b = bid>>10, r = bid&1023, st = r>>4, dt = r&15;
  const int s0 = st*64, d0 = dt*64;
  const int tid = threadIdx.x;
#pragma unroll
  for(int t=0;t<2;t++){
    int cl = tid + t*256; int dr = cl>>3, c = cl&7;
    *(uint4*)&Ls[dr*72 + c*8] = *(const uint4*)(bcT + ((size_t)(b*DM)+d0+dr)*S_ + s0 + c*8);
  }
  __syncthreads();
#pragma unroll
  for(int t=0;t<2;t++){
    int cl = tid + t*256; int sr = cl>>3, c = cl&7;
    unsigned short tmp[8];
#pragma unroll
    for(int j=0;j<8;j++) tmp[j] = Ls[(c*8+j)*72 + sr];
    *(uint4*)(bc + ((size_t)(b*S_)+s0+sr)*DM + d0 + c*8) = *(const uint4*)tmp;
  }
}

// ---------------------------------------------------------------------------
// Conv path (MFMA), unchanged.
// ---------------------------------------------------------------------------
__global__ __launch_bounds__(256) void k_xstage(const float* __restrict__ x,
                                                unsigned short* __restrict__ Asta){
  __shared__ float xs[4][1024];
  const int m = blockIdx.x;            // 0..127
  const int b = m>>6, t = m&63;
  const int tid = threadIdx.x;
  const float* xp = x + (size_t)(b*S_ + 4*t)*DM;
  for(int i=tid; i<4096; i+=256) xs[i>>10][i&1023] = xp[i];
  __syncthreads();
  float v[16];
#pragma unroll
  for(int e=0; e<16; e++) v[e] = xs[e&3][tid*4 + (e>>2)];
  uint4 r0, r1;
  r0.x = pack2(v[0],v[1]);  r0.y = pack2(v[2],v[3]);
  r0.z = pack2(v[4],v[5]);  r0.w = pack2(v[6],v[7]);
  r1.x = pack2(v[8],v[9]);  r1.y = pack2(v[10],v[11]);
  r1.z = pack2(v[12],v[13]); r1.w = pack2(v[14],v[15]);
  unsigned short* op = Asta + (size_t)m*4096 + tid*16;
  *(uint4*)op = r0;
  *(uint4*)(op+8) = r1;
}

__global__ __launch_bounds__(256) void k_gemmconv(const unsigned short* __restrict__ A,
                                                  const unsigned short* __restrict__ Bw,
                                                  float* __restrict__ part){
  __shared__ __align__(16) unsigned short As[128*64];
  __shared__ __align__(16) unsigned short Bs[128*64];
  const int nt = blockIdx.x, kt = blockIdx.y;
  const int n0 = nt<<7;
  const int tid = threadIdx.x, wid = tid>>6, lane = tid&63, quad = lane>>4, tl = lane&15;
  const int mq = (wid&1)*64, nq = (wid>>1)*64;
  f4v acc[4][4];
#pragma unroll
  for(int i=0;i<4;i++)
#pragma unroll
    for(int j=0;j<4;j++) acc[i][j] = (f4v)(0.f);

  for(int kc=kt*1024; kc<kt*1024+1024; kc+=64){
    __syncthreads();
#pragma unroll
    for(int t=0; t<4; t++){
      int cl = tid + t*256, m = cl>>3, c = cl&7;
      uint4 v = *(const uint4*)(A + (size_t)m*4096 + kc + c*8);
      *(uint4*)&As[m*64 + ((c ^ (m&7))<<3)] = v;
      uint4 w = *(const uint4*)(Bw + (size_t)(n0+m)*4096 + kc + c*8);
      *(uint4*)&Bs[m*64 + ((c ^ (m&7))<<3)] = w;
    }
    __syncthreads();
#pragma unroll
    for(int ks=0; ks<2; ks++){
      s8v af[4], bf[4];
#pragma unroll
      for(int i=0;i<4;i++){
        int ml = mq + i*16 + tl;
        af[i] = *(const s8v*)&As[ml*64 + (((ks*4+quad) ^ (ml&7))<<3)];
      }
#pragma unroll
      for(int j=0;j<4;j++){
        int nl = nq + j*16 + tl;
        bf[j] = *(const s8v*)&Bs[nl*64 + (((ks*4+quad) ^ (nl&7))<<3)];
      }
#pragma unroll
      for(int i=0;i<4;i++)
#pragma unroll
        for(int j=0;j<4;j++)
          acc[i][j] = __builtin_amdgcn_mfma_f32_16x16x32_bf16(af[i], bf[j], acc[i][j], 0, 0, 0);
    }
  }
  float* pp = part + (size_t)kt*131072;
#pragma unroll
  for(int i=0;i<4;i++)
#pragma unroll
    for(int r=0;r<4;r++){
      int m = mq + i*16 + quad*4 + r;
#pragma unroll
      for(int j=0;j<4;j++){
        int n = n0 + nq + j*16 + tl;
        pp[m*1024 + n] = acc[i][j][r];
      }
    }
}

__global__ __launch_bounds__(256) void k_convred(const float* __restrict__ part,
                                                 const float* __restrict__ cb,
                                                 unsigned short* __restrict__ kv){
  int i = blockIdx.x*256 + threadIdx.x;   // 131072
  int m = i>>10, o = i&1023;
  float v = part[i] + part[131072+i] + part[262144+i] + part[393216+i] + cb[o];
  int b = m>>6, t = m&63, h = o>>7, hd = o&127;
  kv[((size_t)(b*NH + h)*128 + t)*HDIM + hd] = f2bf(v);
}

__global__ __launch_bounds__(256) void k_gmem(const float* __restrict__ g,
                                              unsigned short* __restrict__ kv){
  int i = blockIdx.x*256 + threadIdx.x;   // 131072 total
  int hd = i & 127, gt = (i>>7)&63, h = (i>>13)&7, b = i>>16;
  kv[((size_t)(b*NH + h)*128 + 64 + gt)*HDIM + hd] = f2bf(g[((size_t)(h*64 + gt))*HDIM + hd]);
}

// ---------------------------------------------------------------------------
// MFMA flash attention, bf16 inputs.
// R10 (post-mortem R4: combined VGPR+AGPR = 148 > 128 cap at 4 waves/EU ->
// spill, 374MB scratch. gfx950 occupancy halves at combined >128 [m69], so
// R3 was really 2 blk/CU — registers, not LDS, were the limiter):
//  - 16 q-rows per wave (QBLK=64/block). Live state: qf16 + st16 + oacc32 +
//    rg16 + addr ~= 100 combined <= 128 -> TRUE 4 waves/EU, 16 waves/CU.
//  - aggregate K-staging doubles (more blocks/panel) but LDS BW and HBM
//    (16MB FETCH, L2-resident panels) have large headroom.
//  - MODE0 grid 960x2 (qt-fastest XCD swizzle: panel-sharers on same L2);
//    MODE1 512x2 = exactly one full residency round.
//  - rest identical to R3: reg-staged K/V, P overlays K (3-barrier loop),
//    max-free softmax, setprio around MFMA clusters.
// ---------------------------------------------------------------------------
template<int MODE>
__global__ __launch_bounds__(256, 4) void k_attn(const unsigned short* __restrict__ xb,
                                                 const unsigned short* __restrict__ kvb,
                                                 unsigned short* __restrict__ outb){
  __shared__ __align__(16) unsigned short sh[17408];  // 34.8 KB
  constexpr int KSo = 0;      // K-tile [64][128] swizzled  (16 KB)
  constexpr int PSo = 0;      // P [64][64] swizzled — overlays K (safe: bar3)
  constexpr int VTo = 8192;   // V^T [128][72]              (18 KB)

  const int b = blockIdx.y;
  int h, n, qt, nkt;
  if(MODE==0){
    int r = blockIdx.x;                  // 960 = 15n * 8h * 8qt
    int s = (r&7)*120 + (r>>3);          // bijective chunked XCD swizzle
    qt = s&7; h = (s>>3)&7; n = s>>6; nkt = 8;
  } else {
    int r = blockIdx.x;                  // 512 = 8h * 64qt
    int s = (r&7)*64 + (r>>3);
    qt = s&63; h = s>>6; n = 0; nkt = 2;
  }

  const int tid  = threadIdx.x;
  const int wid  = tid>>6, lane = tid&63, quad = lane>>4, tl = lane&15;
  const int sQ   = (MODE==0) ? (n*256 + qt*64) : (qt*64);

  // Q fragments: ONE 16-row group per wave (16 q rows x 128 hd)
  s8v qf[4];
  {
    int qr = sQ + wid*16 + tl;
    const unsigned short* qp = xb + ((size_t)(b*S_) + qr)*DM + h*HDIM;
#pragma unroll
    for(int ks=0; ks<4; ks++)
      qf[ks] = *(const s8v*)(qp + ks*32 + quad*8);
  }

  const unsigned short* kbase = (MODE==0)
      ? xb + ((size_t)(b*S_) + n*256)*DM + h*HDIM
      : kvb + (size_t)(b*NH+h)*128*HDIM;
  const int kstride = (MODE==0) ? DM : HDIM;
  const int mrow = (tid&15)*4;     // base t-row of this thread's 4 rows
  const int cg   = tid>>4;         // hd granule (8 ushorts), 0..15

  // prologue: prefetch tile 0 into registers
  uint4 rg[4];
#pragma unroll
  for(int j=0;j<4;j++)
    rg[j] = *(const uint4*)(kbase + (size_t)(mrow+j)*kstride + cg*8);

  f4v oacc[8];
#pragma unroll
  for(int ht=0; ht<8; ht++) oacc[ht] = (f4v)(0.f);
  float l_ = 0.f;

  const float SC2 = 0.12751743f;   // (1/sqrt(128)) * log2(e)

  for(int kt=0; kt<nkt; kt++){
    __syncthreads();               // prev PV done reading P(=K region) and VT
    // --- stage K tile (swizzled) from regs: 4 conflict-free uint4 writes
#pragma unroll
    for(int j=0;j<4;j++){
      int t = mrow + j;
      *(uint4*)&sh[KSo + t*128 + ((cg ^ (t&7))<<3)] = rg[j];
    }
    // --- stage V^T from regs: pack 4 consecutive t per hd, ds_write_b64
    {
      const unsigned int* w0 = (const unsigned int*)&rg[0];
      const unsigned int* w1 = (const unsigned int*)&rg[1];
      const unsigned int* w2 = (const unsigned int*)&rg[2];
      const unsigned int* w3 = (const unsigned int*)&rg[3];
#pragma unroll
      for(int i=0;i<8;i++){
        int w = i>>1;
        unsigned int a, c2;
        if(i&1){ a  = (w0[w]>>16) | (w1[w] & 0xffff0000u);
                 c2 = (w2[w]>>16) | (w3[w] & 0xffff0000u); }
        else   { a  = (w0[w] & 0xffffu) | (w1[w]<<16);
                 c2 = (w2[w] & 0xffffu) | (w3[w]<<16); }
        uint2 u = {a, c2};
        *(uint2*)&sh[VTo + (cg*8+i)*72 + mrow] = u;
      }
    }
    __syncthreads();               // staging visible
    // --- prefetch next K tile into regs (latency hides under compute)
    if(kt+1 < nkt){
      const unsigned short* np = kbase + (size_t)((kt+1)*64 + mrow)*kstride + cg*8;
#pragma unroll
      for(int j=0;j<4;j++) rg[j] = *(const uint4*)(np + (size_t)j*kstride);
    }

    // --- S^T[t][q] = K.Q^T (raw scores, scale folded into exp2)
    f4v st[4];
    __builtin_amdgcn_s_setprio(1);
#pragma unroll
    for(int tt=0; tt<4; tt++){
      st[tt] = (f4v)(0.f);
      int row = tt*16 + tl;
#pragma unroll
      for(int ks=0; ks<4; ks++){
        s8v af = *(const s8v*)&sh[KSo + row*128 + (((ks*4+quad) ^ (row&7))<<3)];
        st[tt] = __builtin_amdgcn_mfma_f32_16x16x32_bf16(af, qf[ks], st[tt], 0, 0, 0);
      }
    }
    __builtin_amdgcn_s_setprio(0);

    // --- softmax, no max subtraction (scores bounded; exp2 arg <= ~27)
    {
      float ps = 0.f;
#pragma unroll
      for(int tt=0; tt<4; tt++)
#pragma unroll
        for(int r=0; r<4; r++){
          float p = exp2f(st[tt][r]*SC2);
          st[tt][r] = p; ps += p;
        }
      ps += __shfl_xor(ps, 16);
      ps += __shfl_xor(ps, 32);
      l_ += ps;
    }

    __syncthreads();               // all waves' QK reads of K done -> P may overlay

    // --- P store: [64][64] XOR-swizzled (granule-8)
    {
      int ql = wid*16 + tl;
#pragma unroll
      for(int tt=0; tt<4; tt++){
        ushort4 u = { f2bf(st[tt][0]), f2bf(st[tt][1]),
                      f2bf(st[tt][2]), f2bf(st[tt][3]) };
        *(ushort4*)&sh[PSo + ql*64 + (((tt*2 + (quad>>1)) ^ (ql&7))<<3) + (quad&1)*4] = u;
      }
    }

    // --- O^T += V^T . P^T  (P rows are wave-private: no barrier needed)
    __builtin_amdgcn_s_setprio(1);
#pragma unroll
    for(int kk=0; kk<2; kk++){
      int ql = wid*16 + tl;
      s8v pb = *(const s8v*)&sh[PSo + ql*64 + (((kk*4+quad) ^ (ql&7))<<3)];
#pragma unroll
      for(int ht=0; ht<8; ht++){
        s8v vf = *(const s8v*)&sh[VTo + (ht*16 + tl)*72 + kk*32 + quad*8];
        oacc[ht] = __builtin_amdgcn_mfma_f32_16x16x32_bf16(vf, pb, oacc[ht], 0, 0, 0);
      }
    }
    __builtin_amdgcn_s_setprio(0);
  }

  // normalize and write out via LDS transpose (64 rows x 136 stride)
  {
    float inv = 1.0f/l_;
#pragma unroll
    for(int ht=0; ht<8; ht++) oacc[ht] *= inv;
  }
  __syncthreads();
  {
    int ql = wid*16 + tl;
#pragma unroll
    for(int ht=0; ht<8; ht++){
      ushort4 u = { f2bf(oacc[ht][0]), f2bf(oacc[ht][1]),
                    f2bf(oacc[ht][2]), f2bf(oacc[ht][3]) };
      *(ushort4*)&sh[ql*136 + ht*16 + quad*4] = u;
    }
  }
  __syncthreads();
  {
    int ql = tid>>2, qu = tid&3;     // 64 rows x 4 quarters
    size_t row = (MODE==0) ? (size_t)((b*NWIN + n)*512 + qt*64 + ql)
                           : (size_t)(b*S_ + qt*64 + ql);
    unsigned short* op = outb + row*DM + h*HDIM + qu*32;
#pragma unroll
    for(int c=0; c<4; c++){
      uint4 v = *(const uint4*)&sh[ql*136 + qu*32 + c*8];
      *(uint4*)(op + c*8) = v;
    }
  }
}

// ---------------------------------------------------------------------------
// Triangular-weighted overlap-add
// ---------------------------------------------------------------------------
__global__ __launch_bounds__(256) void k_combine(const unsigned short* __restrict__ wso,
                                                 unsigned short* __restrict__ loc){
  const int bid = blockIdx.x;          // B*S
  const int b = bid >> 12, s = bid & 4095;
  const int tid = threadIdx.x;
  const int nhi = s >> 8, sl = s & 255;
  const int c0 = tid*4;
  float n0=0.f, n1=0.f, n2=0.f, n3=0.f, den=0.f;
  if(nhi <= 14){
    float tr = 0.5f + (float)sl*(1.0f/511.0f);
    den += tr;
    uint2 u = *(const uint2*)(wso + (size_t)((b*NWIN + nhi)*512 + sl)*DM + c0);
    n0 += tr*f_lo(u.x); n1 += tr*f_hi(u.x); n2 += tr*f_lo(u.y); n3 += tr*f_hi(u.y);
  }
  if(nhi >= 1){
    int q2 = sl + 256;
    float tr = 0.5f + (float)q2*(1.0f/511.0f);
    den += tr;
    uint2 u = *(const uint2*)(wso + (size_t)((b*NWIN + nhi-1)*512 + q2)*DM + c0);
    n0 += tr*f_lo(u.x); n1 += tr*f_hi(u.x); n2 += tr*f_lo(u.y); n3 += tr*f_hi(u.y);
  }
  float di = 1.0f/den;
  uint2 o; o.x = pack2(n0*di, n1*di); o.y = pack2(n2*di, n3*di);
  *(uint2*)(loc + (size_t)(b*S_ + s)*DM + c0) = o;
}

// ---------------------------------------------------------------------------
// Weight transpose+convert: W [K][1024] fp32 -> WT [1024][K] bf16 (64x64 tiles)
// ---------------------------------------------------------------------------
__global__ __launch_bounds__(256) void k_wcvt(const float* __restrict__ W,
                                              unsigned short* __restrict__ WT, int K){
  __shared__ float Ls[64][68];
  int kt = blockIdx.x >> 4, nt = blockIdx.x & 15;
  int k0 = kt<<6, n0 = nt<<6;
  int tid = threadIdx.x;
#pragma unroll
  for(int p=0; p<4; p++){
    int r = p*16 + (tid>>4), c4 = (tid&15)*4;
    float4 v = *(const float4*)(W + (size_t)(k0+r)*1024 + n0 + c4);
    *(float4*)&Ls[r][c4] = v;
  }
  __syncthreads();
  int nn = tid>>2, kq = tid&3;
#pragma unroll
  for(int c=0; c<4; c++){
    int k = kq*16 + c*4;
    ushort4 u = { f2bf(Ls[k+0][nn]), f2bf(Ls[k+1][nn]), f2bf(Ls[k+2][nn]), f2bf(Ls[k+3][nn]) };
    *(ushort4*)(WT + (size_t)(n0+nn)*K + k0 + k) = u;
  }
}

// ---------------------------------------------------------------------------
// MFMA GEMM 128x128 tile, BK=64, XOR-swizzled LDS, 4 waves x (64x64 quadrant).
// MODE 0: + sigmoid gate mix epilogue -> mixed (bf16).  MODE 1: + bias -> out fp32.
// ---------------------------------------------------------------------------
template<int MODE>
__global__ __launch_bounds__(256) void k_gemm2(const unsigned short* __restrict__ A0,
                                               const unsigned short* __restrict__ A1,
                                               const unsigned short* __restrict__ WT,
                                               const float* __restrict__ bias,
                                               const unsigned short* __restrict__ loc,
                                               const unsigned short* __restrict__ glo,
                                               const unsigned short* __restrict__ bcb,
                                               unsigned short* __restrict__ outb,
                                               float* __restrict__ outf){
  const int KTOT = (MODE==0) ? 2048 : 1024;
  __shared__ __align__(16) unsigned short As[128*64];
  __shared__ __align__(16) unsigned short Bs[128*64];
  const int mt = blockIdx.x >> 3, nt = blockIdx.x & 7;
  const int m0 = mt<<7, n0 = nt<<7;
  const int tid = threadIdx.x, wid = tid>>6, lane = tid&63, quad = lane>>4, tl = lane&15;
  const int mq = (wid&1)*64, nq = (wid>>1)*64;
  f4v acc[4][4];
#pragma unroll
  for(int i=0;i<4;i++)
#pragma unroll
    for(int j=0;j<4;j++) acc[i][j] = (f4v)(0.f);

  for(int kc=0; kc<KTOT; kc+=64){
    __syncthreads();
    const unsigned short* Ab = (MODE==0 && kc>=1024) ? A1 : A0;
    const int kb = (MODE==0) ? (kc & 1023) : kc;
#pragma unroll
    for(int t=0; t<4; t++){
      int cl = tid + t*256, m = cl>>3, c = cl&7;
      uint4 v = *(const uint4*)(Ab + (size_t)(m0+m)*1024 + kb + c*8);
      *(uint4*)&As[m*64 + ((c ^ (m&7))<<3)] = v;
      uint4 w = *(const uint4*)(WT + (size_t)(n0+m)*KTOT + kc + c*8);
      *(uint4*)&Bs[m*64 + ((c ^ (m&7))<<3)] = w;
    }
    __syncthreads();
#pragma unroll
    for(int ks=0; ks<2; ks++){
      s8v af[4], bf[4];
#pragma unroll
      for(int i=0;i<4;i++){
        int ml = mq + i*16 + tl;
        af[i] = *(const s8v*)&As[ml*64 + (((ks*4+quad) ^ (ml&7))<<3)];
      }
#pragma unroll
      for(int j=0;j<4;j++){
        int nl = nq + j*16 + tl;
        bf[j] = *(const s8v*)&Bs[nl*64 + (((ks*4+quad) ^ (nl&7))<<3)];
      }
#pragma unroll
      for(int i=0;i<4;i++)
#pragma unroll
        for(int j=0;j<4;j++)
          acc[i][j] = __builtin_amdgcn_mfma_f32_16x16x32_bf16(af[i], bf[j], acc[i][j], 0, 0, 0);
    }
  }

#pragma unroll
  for(int i=0;i<4;i++){
#pragma unroll
    for(int r=0;r<4;r++){
      int m = m0 + mq + i*16 + quad*4 + r;
      size_t rowb = (size_t)m * 1024;
#pragma unroll
      for(int j=0;j<4;j++){
        int nn = n0 + nq + j*16 + tl;
        float v = acc[i][j][r] + bias[nn];
        if(MODE==0){
          float g  = 1.0f/(1.0f + __expf(-v));
          float lv = f_lo((unsigned int)loc[rowb+nn]);
          float gv = f_lo((unsigned int)glo[rowb+nn]);
          float bv = f_lo((unsigned int)bcb[rowb+nn]);
          outb[rowb+nn] = f2bf(g*lv + (1.0f-g)*gv + bv);
        } else {
          outf[rowb+nn] = v;
        }
      }
    }
  }
}

extern "C" void kernel_launch(void* const* d_in, const int* in_sizes, int n_in,
                              void* d_out, int out_size, void* d_ws, size_t ws_size,
                              hipStream_t stream){
  const float* x  = (const float*)d_in[0];
  const float* gm = (const float*)d_in[1];
  const float* cw = (const float*)d_in[2];
  const float* cb = (const float*)d_in[3];
  const float* mw = (const float*)d_in[4];
  const float* mb = (const float*)d_in[5];
  const float* ow = (const float*)d_in[6];
  const float* ob = (const float*)d_in[7];
  float* out = (float*)d_out;

  char* ws = (char*)d_ws;
  const size_t SZ = (size_t)B_*S_*DM*2;                 // 16.78 MB per bf16 field
  unsigned short* localb = (unsigned short*)(ws);
  unsigned short* globb  = (unsigned short*)(ws + SZ);
  unsigned short* bcb    = (unsigned short*)(ws + 2*SZ);
  unsigned short* kvb    = (unsigned short*)(ws + 3*SZ);
  unsigned short* wso    = (unsigned short*)(ws + 3*SZ + 524288);
  unsigned short* mixed  = wso;                          // first 16.78 MB of wso region
  unsigned short* wt1    = (unsigned short*)(ws + 3*SZ + 524288 + SZ);            // 4 MB
  unsigned short* wt2    = (unsigned short*)(ws + 3*SZ + 524288 + SZ + 4194304);  // 2 MB
  // conv-path scratch overlays localb region (consumed before k_xbf)
  unsigned short* cwb    = (unsigned short*)(ws);               // 8 MB bf16 [1024][4096]
  unsigned short* asta   = (unsigned short*)(ws + 8388608);     // 1 MB bf16 [128][4096]
  float*          cpart  = (float*)        (ws + 9437184);      // 2 MB fp32 [4][128][1024]
  // overlays: xT over globb+bcb (dead until attn<1>/bcxpose); bcT over wso
  float*          xT     = (float*)(ws + SZ);                   // 33.5 MB fp32 [b][1024][4096]
  unsigned short* bcT    = wso;                                 // 16.78 MB bf16 [b][1024][4096]
  unsigned short* xbf    = (unsigned short*)(ws);               // 16.78 MB bf16 x (over conv scratch)

  // conv path (uses ws[0..11.5M])
  k_cvtbf   <<<2048, 256, 0, stream>>>(cw, cwb);
  k_xstage  <<<128,  256, 0, stream>>>(x, asta);
  k_gemmconv<<<dim3(8,4), 256, 0, stream>>>(asta, cwb, cpart);
  k_convred <<<512,  256, 0, stream>>>(cpart, cb, kvb);
  k_gmem    <<<512,  256, 0, stream>>>(gm, kvb);
  // diffusion path (transposed space)
  k_xposef  <<<2048, 256, 0, stream>>>(x, xT);
  k_diffuseT<<<1024, 256, 0, stream>>>(xT, bcT);
  k_bcxpose <<<2048, 256, 0, stream>>>(bcT, bcb);
  // bf16 x for attention (overwrites conv scratch)
  k_cvtbf   <<<4096, 256, 0, stream>>>(x, xbf);
  k_attn<1> <<<dim3(512,2), 256, 0, stream>>>(xbf, kvb, globb);
  k_attn<0> <<<dim3(960,2), 256, 0, stream>>>(xbf, kvb, wso);   // overwrites bcT (dead)
  k_combine <<<8192, 256, 0, stream>>>(wso, localb);            // overwrites xbf (dead)
  k_wcvt    <<<512,  256, 0, stream>>>(mw, wt1, 2048);
  k_wcvt    <<<256,  256, 0, stream>>>(ow, wt2, 1024);
  k_gemm2<0><<<512, 256, 0, stream>>>(localb, globb, wt1, mb, localb, globb, bcb, mixed, nullptr);
  k_gemm2<1><<<512, 256, 0, stream>>>(mixed, nullptr, wt2, ob, nullptr, nullptr, nullptr, nullptr, out);
}

// Round 6
// 366.145 us; speedup vs baseline: 1.4481x; 1.0636x over previous
//
#include <hip/hip_runtime.h>
#include <cstdint>

#define B_   2
#define S_   4096
#define DM   1024
#define NH   8
#define HDIM 128
#define NWIN 15

typedef __attribute__((ext_vector_type(8))) short s8v;   // 8 bf16 (4 VGPRs)
typedef __attribute__((ext_vector_type(4))) float f4v;   // 4 fp32 acc

__device__ __forceinline__ float f_lo(unsigned int u){
  union { unsigned int i; float f; } v; v.i = u << 16; return v.f;
}
__device__ __forceinline__ float f_hi(unsigned int u){
  union { unsigned int i; float f; } v; v.i = u & 0xffff0000u; return v.f;
}
__device__ __forceinline__ unsigned short f2bf(float f){
  unsigned int x = __float_as_uint(f);
  x += 0x7fffu + ((x >> 16) & 1u);
  return (unsigned short)(x >> 16);
}
__device__ __forceinline__ unsigned int pack2(float a, float b){
  return (unsigned int)f2bf(a) | ((unsigned int)f2bf(b) << 16);
}
// async global->LDS DMA, 16B per lane; LDS dest = wave-uniform base + lane*16
__device__ __forceinline__ void gl16(const unsigned short* g, unsigned short* l){
  __builtin_amdgcn_global_load_lds(
      (const __attribute__((address_space(1))) unsigned int*)g,
      (__attribute__((address_space(3))) unsigned int*)l, 16, 0, 0);
}

// ---------------------------------------------------------------------------
// Generic fp32 -> bf16 convert (8 elems/thread). Used for cw (2048 blocks).
// ---------------------------------------------------------------------------
__global__ __launch_bounds__(256) void k_cvtbf(const float* __restrict__ src,
                                               unsigned short* __restrict__ dst){
  size_t i = ((size_t)blockIdx.x*256 + threadIdx.x)*8;
  float4 a = *(const float4*)(src + i);
  float4 b = *(const float4*)(src + i + 4);
  uint4 r; r.x = pack2(a.x,a.y); r.y = pack2(a.z,a.w);
  r.z = pack2(b.x,b.y); r.w = pack2(b.z,b.w);
  *(uint4*)(dst + i) = r;
}

// ---------------------------------------------------------------------------
// fp32 transpose: x [b][s][1024] -> xT [b][1024][s].  64x64 tiles.
// R11: also emits bf16 x (xbf) in the load phase — kills the separate
// k_cvtbf(x) pass (x is already in registers here).
// ---------------------------------------------------------------------------
__global__ __launch_bounds__(256) void k_xposef(const float* __restrict__ x,
                                                float* __restrict__ xT,
                                                unsigned short* __restrict__ xbf){
  __shared__ float Ls[64][68];
  const int bid = blockIdx.x;             // b*1024 + st*16 + dt
  const int b = bid>>10, r = bid&1023, st = r>>4, dt = r&15;
  const int s0 = st*64, d0 = dt*64;
  const int tid = threadIdx.x;
#pragma unroll
  for(int p=0;p<4;p++){
    int rr = p*16 + (tid>>4), c4 = (tid&15)*4;
    float4 v = *(const float4*)(x + ((size_t)(b*S_)+s0+rr)*DM + d0 + c4);
    *(float4*)&Ls[rr][c4] = v;
    ushort4 u = { f2bf(v.x), f2bf(v.y), f2bf(v.z), f2bf(v.w) };
    *(ushort4*)(xbf + ((size_t)(b*S_)+s0+rr)*DM + d0 + c4) = u;
  }
  __syncthreads();
#pragma unroll
  for(int p=0;p<4;p++){
    int dr = p*16 + (tid>>4), c4 = (tid&15)*4;
    float4 v = { Ls[c4+0][dr], Ls[c4+1][dr], Ls[c4+2][dr], Ls[c4+3][dr] };
    *(float4*)(xT + ((size_t)(b*DM)+d0+dr)*S_ + s0 + c4) = v;
  }
}

// ---------------------------------------------------------------------------
// Diffusion in transposed space. R11: stages 8..11 have stride multiple of
// 256 = thread stride, so their neighbors live in the SAME thread's regs —
// 12 LDS stages + barriers -> 8; last 4 stages are pure register math.
// ---------------------------------------------------------------------------
__global__ __launch_bounds__(256) void k_diffuseT(const float* __restrict__ xT,
                                                  unsigned short* __restrict__ bcT){
  __shared__ float bufA[2][4096];
  __shared__ float bufB[2][4096];
  const int b  = blockIdx.x >> 9;
  const int d0 = (blockIdx.x & 511) * 2;
  const int tid = threadIdx.x;
  float curA_[32], curB_[32], res[32];
#pragma unroll
  for(int k=0;k<32;k++){
    int e = tid + (k<<8); int ch = e>>12; int s = e&4095;
    float v = xT[((size_t)(b*DM)+d0+ch)*S_ + s];
    curA_[k] = v; res[k] = 0.f; bufA[ch][s] = v;
  }
  __syncthreads();
#pragma unroll 1
  for(int st=0; st<8; st++){
    const int stride = 1<<st;
    float (*src)[4096] = (st&1) ? bufB : bufA;
    float (*dst)[4096] = (st&1) ? bufA : bufB;
#pragma unroll
    for(int k=0;k<32;k++){
      int e = tid + (k<<8); int ch=e>>12; int s=e&4095;
      float c = curA_[k] + 0.5f*(src[ch][(s-stride)&4095] + src[ch][(s+stride)&4095]);
      dst[ch][s] = c; curA_[k] = c; res[k] += c;
    }
    __syncthreads();
  }
  // stages 8..11 in registers: neighbor reg index = ch*16 + ((kk +- m)&15)
#pragma unroll
  for(int k=0;k<32;k++){
    int ch=k>>4, kk=k&15;
    curB_[k] = curA_[k] + 0.5f*(curA_[ch*16 + ((kk-1)&15)] + curA_[ch*16 + ((kk+1)&15)]);
    res[k] += curB_[k];
  }
#pragma unroll
  for(int k=0;k<32;k++){
    int ch=k>>4, kk=k&15;
    curA_[k] = curB_[k] + 0.5f*(curB_[ch*16 + ((kk-2)&15)] + curB_[ch*16 + ((kk+2)&15)]);
    res[k] += curA_[k];
  }
#pragma unroll
  for(int k=0;k<32;k++){
    int ch=k>>4, kk=k&15;
    curB_[k] = curA_[k] + 0.5f*(curA_[ch*16 + ((kk-4)&15)] + curA_[ch*16 + ((kk+4)&15)]);
    res[k] += curB_[k];
  }
#pragma unroll
  for(int k=0;k<32;k++){
    int ch=k>>4, kk=k&15;
    curA_[k] = curB_[k] + 0.5f*(curB_[ch*16 + ((kk-8)&15)] + curB_[ch*16 + ((kk+8)&15)]);
    res[k] += curA_[k];
  }
#pragma unroll
  for(int k=0;k<32;k++){
    int e = tid + (k<<8); int ch=e>>12; int s=e&4095;
    bcT[((size_t)(b*DM)+d0+ch)*S_ + s] = f2bf(res[k]*(1.0f/13.0f));
  }
}

// ---------------------------------------------------------------------------
// bf16 transpose back: bcT [b][1024][s] -> bc [b][s][1024]. 64x64 tiles.
// ---------------------------------------------------------------------------
__global__ __launch_bounds__(256) void k_bcxpose(const unsigned short* __restrict__ bcT,
                                                 unsigned short* __restrict__ bc){
  __shared__ unsigned short Ls[64*72];
  const int bid = blockIdx.x;             // b*1024 + st*16 + dt
  const int b = bid>>10, r = bid&1023, st = r>>4, dt = r&15;
  const int s0 = st*64, d0 = dt*64;
  const int tid = threadIdx.x;
#pragma unroll
  for(int t=0;t<2;t++){
    int cl = tid + t*256; int dr = cl>>3, c = cl&7;
    *(uint4*)&Ls[dr*72 + c*8] = *(const uint4*)(bcT + ((size_t)(b*DM)+d0+dr)*S_ + s0 + c*8);
  }
  __syncthreads();
#pragma unroll
  for(int t=0;t<2;t++){
    int cl = tid + t*256; int sr = cl>>3, c = cl&7;
    unsigned short tmp[8];
#pragma unroll
    for(int j=0;j<8;j++) tmp[j] = Ls[(c*8+j)*72 + sr];
    *(uint4*)(bc + ((size_t)(b*S_)+s0+sr)*DM + d0 + c*8) = *(const uint4*)tmp;
  }
}

// ---------------------------------------------------------------------------
// Conv path (MFMA), unchanged.
// ---------------------------------------------------------------------------
__global__ __launch_bounds__(256) void k_xstage(const float* __restrict__ x,
                                                unsigned short* __restrict__ Asta){
  __shared__ float xs[4][1024];
  const int m = blockIdx.x;            // 0..127
  const int b = m>>6, t = m&63;
  const int tid = threadIdx.x;
  const float* xp = x + (size_t)(b*S_ + 4*t)*DM;
  for(int i=tid; i<4096; i+=256) xs[i>>10][i&1023] = xp[i];
  __syncthreads();
  float v[16];
#pragma unroll
  for(int e=0; e<16; e++) v[e] = xs[e&3][tid*4 + (e>>2)];
  uint4 r0, r1;
  r0.x = pack2(v[0],v[1]);  r0.y = pack2(v[2],v[3]);
  r0.z = pack2(v[4],v[5]);  r0.w = pack2(v[6],v[7]);
  r1.x = pack2(v[8],v[9]);  r1.y = pack2(v[10],v[11]);
  r1.z = pack2(v[12],v[13]); r1.w = pack2(v[14],v[15]);
  unsigned short* op = Asta + (size_t)m*4096 + tid*16;
  *(uint4*)op = r0;
  *(uint4*)(op+8) = r1;
}

__global__ __launch_bounds__(256) void k_gemmconv(const unsigned short* __restrict__ A,
                                                  const unsigned short* __restrict__ Bw,
                                                  float* __restrict__ part){
  __shared__ __align__(16) unsigned short As[128*64];
  __shared__ __align__(16) unsigned short Bs[128*64];
  const int nt = blockIdx.x, kt = blockIdx.y;
  const int n0 = nt<<7;
  const int tid = threadIdx.x, wid = tid>>6, lane = tid&63, quad = lane>>4, tl = lane&15;
  const int mq = (wid&1)*64, nq = (wid>>1)*64;
  f4v acc[4][4];
#pragma unroll
  for(int i=0;i<4;i++)
#pragma unroll
    for(int j=0;j<4;j++) acc[i][j] = (f4v)(0.f);

  for(int kc=kt*1024; kc<kt*1024+1024; kc+=64){
    __syncthreads();
#pragma unroll
    for(int t=0; t<4; t++){
      int cl = tid + t*256, m = cl>>3, c = cl&7;
      uint4 v = *(const uint4*)(A + (size_t)m*4096 + kc + c*8);
      *(uint4*)&As[m*64 + ((c ^ (m&7))<<3)] = v;
      uint4 w = *(const uint4*)(Bw + (size_t)(n0+m)*4096 + kc + c*8);
      *(uint4*)&Bs[m*64 + ((c ^ (m&7))<<3)] = w;
    }
    __syncthreads();
#pragma unroll
    for(int ks=0; ks<2; ks++){
      s8v af[4], bf[4];
#pragma unroll
      for(int i=0;i<4;i++){
        int ml = mq + i*16 + tl;
        af[i] = *(const s8v*)&As[ml*64 + (((ks*4+quad) ^ (ml&7))<<3)];
      }
#pragma unroll
      for(int j=0;j<4;j++){
        int nl = nq + j*16 + tl;
        bf[j] = *(const s8v*)&Bs[nl*64 + (((ks*4+quad) ^ (nl&7))<<3)];
      }
#pragma unroll
      for(int i=0;i<4;i++)
#pragma unroll
        for(int j=0;j<4;j++)
          acc[i][j] = __builtin_amdgcn_mfma_f32_16x16x32_bf16(af[i], bf[j], acc[i][j], 0, 0, 0);
    }
  }
  float* pp = part + (size_t)kt*131072;
#pragma unroll
  for(int i=0;i<4;i++)
#pragma unroll
    for(int r=0;r<4;r++){
      int m = mq + i*16 + quad*4 + r;
#pragma unroll
      for(int j=0;j<4;j++){
        int n = n0 + nq + j*16 + tl;
        pp[m*1024 + n] = acc[i][j][r];
      }
    }
}

__global__ __launch_bounds__(256) void k_convred(const float* __restrict__ part,
                                                 const float* __restrict__ cb,
                                                 unsigned short* __restrict__ kv){
  int i = blockIdx.x*256 + threadIdx.x;   // 131072
  int m = i>>10, o = i&1023;
  float v = part[i] + part[131072+i] + part[262144+i] + part[393216+i] + cb[o];
  int b = m>>6, t = m&63, h = o>>7, hd = o&127;
  kv[((size_t)(b*NH + h)*128 + t)*HDIM + hd] = f2bf(v);
}

__global__ __launch_bounds__(256) void k_gmem(const float* __restrict__ g,
                                              unsigned short* __restrict__ kv){
  int i = blockIdx.x*256 + threadIdx.x;   // 131072 total
  int hd = i & 127, gt = (i>>7)&63, h = (i>>13)&7, b = i>>16;
  kv[((size_t)(b*NH + h)*128 + 64 + gt)*HDIM + hd] = f2bf(g[((size_t)(h*64 + gt))*HDIM + hd]);
}

// ---------------------------------------------------------------------------
// MFMA flash attention — UNCHANGED from R5 (verified 77 us; LDS-pipe-bound,
// restructure deferred). See R5 comments.
// ---------------------------------------------------------------------------
template<int MODE>
__global__ __launch_bounds__(256, 4) void k_attn(const unsigned short* __restrict__ xb,
                                                 const unsigned short* __restrict__ kvb,
                                                 unsigned short* __restrict__ outb){
  __shared__ __align__(16) unsigned short sh[17408];  // 34.8 KB
  constexpr int KSo = 0;      // K-tile [64][128] swizzled  (16 KB)
  constexpr int PSo = 0;      // P [64][64] swizzled — overlays K (safe: bar3)
  constexpr int VTo = 8192;   // V^T [128][72]              (18 KB)

  const int b = blockIdx.y;
  int h, n, qt, nkt;
  if(MODE==0){
    int r = blockIdx.x;                  // 960 = 15n * 8h * 8qt
    int s = (r&7)*120 + (r>>3);          // bijective chunked XCD swizzle
    qt = s&7; h = (s>>3)&7; n = s>>6; nkt = 8;
  } else {
    int r = blockIdx.x;                  // 512 = 8h * 64qt
    int s = (r&7)*64 + (r>>3);
    qt = s&63; h = s>>6; n = 0; nkt = 2;
  }

  const int tid  = threadIdx.x;
  const int wid  = tid>>6, lane = tid&63, quad = lane>>4, tl = lane&15;
  const int sQ   = (MODE==0) ? (n*256 + qt*64) : (qt*64);

  // Q fragments: ONE 16-row group per wave (16 q rows x 128 hd)
  s8v qf[4];
  {
    int qr = sQ + wid*16 + tl;
    const unsigned short* qp = xb + ((size_t)(b*S_) + qr)*DM + h*HDIM;
#pragma unroll
    for(int ks=0; ks<4; ks++)
      qf[ks] = *(const s8v*)(qp + ks*32 + quad*8);
  }

  const unsigned short* kbase = (MODE==0)
      ? xb + ((size_t)(b*S_) + n*256)*DM + h*HDIM
      : kvb + (size_t)(b*NH+h)*128*HDIM;
  const int kstride = (MODE==0) ? DM : HDIM;
  const int mrow = (tid&15)*4;     // base t-row of this thread's 4 rows
  const int cg   = tid>>4;         // hd granule (8 ushorts), 0..15

  // prologue: prefetch tile 0 into registers
  uint4 rg[4];
#pragma unroll
  for(int j=0;j<4;j++)
    rg[j] = *(const uint4*)(kbase + (size_t)(mrow+j)*kstride + cg*8);

  f4v oacc[8];
#pragma unroll
  for(int ht=0; ht<8; ht++) oacc[ht] = (f4v)(0.f);
  float l_ = 0.f;

  const float SC2 = 0.12751743f;   // (1/sqrt(128)) * log2(e)

  for(int kt=0; kt<nkt; kt++){
    __syncthreads();               // prev PV done reading P(=K region) and VT
    // --- stage K tile (swizzled) from regs: 4 conflict-free uint4 writes
#pragma unroll
    for(int j=0;j<4;j++){
      int t = mrow + j;
      *(uint4*)&sh[KSo + t*128 + ((cg ^ (t&7))<<3)] = rg[j];
    }
    // --- stage V^T from regs: pack 4 consecutive t per hd, ds_write_b64
    {
      const unsigned int* w0 = (const unsigned int*)&rg[0];
      const unsigned int* w1 = (const unsigned int*)&rg[1];
      const unsigned int* w2 = (const unsigned int*)&rg[2];
      const unsigned int* w3 = (const unsigned int*)&rg[3];
#pragma unroll
      for(int i=0;i<8;i++){
        int w = i>>1;
        unsigned int a, c2;
        if(i&1){ a  = (w0[w]>>16) | (w1[w] & 0xffff0000u);
                 c2 = (w2[w]>>16) | (w3[w] & 0xffff0000u); }
        else   { a  = (w0[w] & 0xffffu) | (w1[w]<<16);
                 c2 = (w2[w] & 0xffffu) | (w3[w]<<16); }
        uint2 u = {a, c2};
        *(uint2*)&sh[VTo + (cg*8+i)*72 + mrow] = u;
      }
    }
    __syncthreads();               // staging visible
    // --- prefetch next K tile into regs (latency hides under compute)
    if(kt+1 < nkt){
      const unsigned short* np = kbase + (size_t)((kt+1)*64 + mrow)*kstride + cg*8;
#pragma unroll
      for(int j=0;j<4;j++) rg[j] = *(const uint4*)(np + (size_t)j*kstride);
    }

    // --- S^T[t][q] = K.Q^T (raw scores, scale folded into exp2)
    f4v st[4];
    __builtin_amdgcn_s_setprio(1);
#pragma unroll
    for(int tt=0; tt<4; tt++){
      st[tt] = (f4v)(0.f);
      int row = tt*16 + tl;
#pragma unroll
      for(int ks=0; ks<4; ks++){
        s8v af = *(const s8v*)&sh[KSo + row*128 + (((ks*4+quad) ^ (row&7))<<3)];
        st[tt] = __builtin_amdgcn_mfma_f32_16x16x32_bf16(af, qf[ks], st[tt], 0, 0, 0);
      }
    }
    __builtin_amdgcn_s_setprio(0);

    // --- softmax, no max subtraction (scores bounded; exp2 arg <= ~27)
    {
      float ps = 0.f;
#pragma unroll
      for(int tt=0; tt<4; tt++)
#pragma unroll
        for(int r=0; r<4; r++){
          float p = exp2f(st[tt][r]*SC2);
          st[tt][r] = p; ps += p;
        }
      ps += __shfl_xor(ps, 16);
      ps += __shfl_xor(ps, 32);
      l_ += ps;
    }

    __syncthreads();               // all waves' QK reads of K done -> P may overlay

    // --- P store: [64][64] XOR-swizzled (granule-8)
    {
      int ql = wid*16 + tl;
#pragma unroll
      for(int tt=0; tt<4; tt++){
        ushort4 u = { f2bf(st[tt][0]), f2bf(st[tt][1]),
                      f2bf(st[tt][2]), f2bf(st[tt][3]) };
        *(ushort4*)&sh[PSo + ql*64 + (((tt*2 + (quad>>1)) ^ (ql&7))<<3) + (quad&1)*4] = u;
      }
    }

    // --- O^T += V^T . P^T  (P rows are wave-private: no barrier needed)
    __builtin_amdgcn_s_setprio(1);
#pragma unroll
    for(int kk=0; kk<2; kk++){
      int ql = wid*16 + tl;
      s8v pb = *(const s8v*)&sh[PSo + ql*64 + (((kk*4+quad) ^ (ql&7))<<3)];
#pragma unroll
      for(int ht=0; ht<8; ht++){
        s8v vf = *(const s8v*)&sh[VTo + (ht*16 + tl)*72 + kk*32 + quad*8];
        oacc[ht] = __builtin_amdgcn_mfma_f32_16x16x32_bf16(vf, pb, oacc[ht], 0, 0, 0);
      }
    }
    __builtin_amdgcn_s_setprio(0);
  }

  // normalize and write out via LDS transpose (64 rows x 136 stride)
  {
    float inv = 1.0f/l_;
#pragma unroll
    for(int ht=0; ht<8; ht++) oacc[ht] *= inv;
  }
  __syncthreads();
  {
    int ql = wid*16 + tl;
#pragma unroll
    for(int ht=0; ht<8; ht++){
      ushort4 u = { f2bf(oacc[ht][0]), f2bf(oacc[ht][1]),
                    f2bf(oacc[ht][2]), f2bf(oacc[ht][3]) };
      *(ushort4*)&sh[ql*136 + ht*16 + quad*4] = u;
    }
  }
  __syncthreads();
  {
    int ql = tid>>2, qu = tid&3;     // 64 rows x 4 quarters
    size_t row = (MODE==0) ? (size_t)((b*NWIN + n)*512 + qt*64 + ql)
                           : (size_t)(b*S_ + qt*64 + ql);
    unsigned short* op = outb + row*DM + h*HDIM + qu*32;
#pragma unroll
    for(int c=0; c<4; c++){
      uint4 v = *(const uint4*)&sh[ql*136 + qu*32 + c*8];
      *(uint4*)(op + c*8) = v;
    }
  }
}

// ---------------------------------------------------------------------------
// Triangular-weighted overlap-add
// ---------------------------------------------------------------------------
__global__ __launch_bounds__(256) void k_combine(const unsigned short* __restrict__ wso,
                                                 unsigned short* __restrict__ loc){
  const int bid = blockIdx.x;          // B*S
  const int b = bid >> 12, s = bid & 4095;
  const int tid = threadIdx.x;
  const int nhi = s >> 8, sl = s & 255;
  const int c0 = tid*4;
  float n0=0.f, n1=0.f, n2=0.f, n3=0.f, den=0.f;
  if(nhi <= 14){
    float tr = 0.5f + (float)sl*(1.0f/511.0f);
    den += tr;
    uint2 u = *(const uint2*)(wso + (size_t)((b*NWIN + nhi)*512 + sl)*DM + c0);
    n0 += tr*f_lo(u.x); n1 += tr*f_hi(u.x); n2 += tr*f_lo(u.y); n3 += tr*f_hi(u.y);
  }
  if(nhi >= 1){
    int q2 = sl + 256;
    float tr = 0.5f + (float)q2*(1.0f/511.0f);
    den += tr;
    uint2 u = *(const uint2*)(wso + (size_t)((b*NWIN + nhi-1)*512 + q2)*DM + c0);
    n0 += tr*f_lo(u.x); n1 += tr*f_hi(u.x); n2 += tr*f_lo(u.y); n3 += tr*f_hi(u.y);
  }
  float di = 1.0f/den;
  uint2 o; o.x = pack2(n0*di, n1*di); o.y = pack2(n2*di, n3*di);
  *(uint2*)(loc + (size_t)(b*S_ + s)*DM + c0) = o;
}

// ---------------------------------------------------------------------------
// Weight transpose+convert: W [K][1024] fp32 -> WT [1024][K] bf16 (64x64 tiles)
// ---------------------------------------------------------------------------
__global__ __launch_bounds__(256) void k_wcvt(const float* __restrict__ W,
                                              unsigned short* __restrict__ WT, int K){
  __shared__ float Ls[64][68];
  int kt = blockIdx.x >> 4, nt = blockIdx.x & 15;
  int k0 = kt<<6, n0 = nt<<6;
  int tid = threadIdx.x;
#pragma unroll
  for(int p=0; p<4; p++){
    int r = p*16 + (tid>>4), c4 = (tid&15)*4;
    float4 v = *(const float4*)(W + (size_t)(k0+r)*1024 + n0 + c4);
    *(float4*)&Ls[r][c4] = v;
  }
  __syncthreads();
  int nn = tid>>2, kq = tid&3;
#pragma unroll
  for(int c=0; c<4; c++){
    int k = kq*16 + c*4;
    ushort4 u = { f2bf(Ls[k+0][nn]), f2bf(Ls[k+1][nn]), f2bf(Ls[k+2][nn]), f2bf(Ls[k+3][nn]) };
    *(ushort4*)(WT + (size_t)(n0+nn)*K + k0 + k) = u;
  }
}

// ---------------------------------------------------------------------------
// MFMA GEMM 128x128 tile, BK=64, XOR-swizzled LDS, 4 waves x (64x64 quadrant).
// R11: staging via global_load_lds (16B DMA) with PRE-SWIZZLED per-lane global
// source + linear LDS dest (rule #21).  Lane l of wave w, call i covers
// dest row m = w*32+i*8+(l>>3), slot l&7 holding chunk c = (l&7)^(m&7);
// m&7 == l>>3, so c = (l&7)^(l>>3) is lane-constant.  Removes 8 uint4
// staging regs + staging VALU (m97 ladder: reg-staged 646 TF -> DMA 874 TF).
// launch_bounds(256,3): cap 170 regs — acc64 AGPR + ~65 VGPR fits safely.
// MODE 0: + sigmoid gate mix epilogue -> mixed (bf16).  MODE 1: + bias -> out fp32.
// ---------------------------------------------------------------------------
template<int MODE>
__global__ __launch_bounds__(256, 3) void k_gemm2(const unsigned short* __restrict__ A0,
                                               const unsigned short* __restrict__ A1,
                                               const unsigned short* __restrict__ WT,
                                               const float* __restrict__ bias,
                                               const unsigned short* __restrict__ loc,
                                               const unsigned short* __restrict__ glo,
                                               const unsigned short* __restrict__ bcb,
                                               unsigned short* __restrict__ outb,
                                               float* __restrict__ outf){
  const int KTOT = (MODE==0) ? 2048 : 1024;
  __shared__ __align__(16) unsigned short As[128*64];
  __shared__ __align__(16) unsigned short Bs[128*64];
  const int mt = blockIdx.x >> 3, nt = blockIdx.x & 7;
  const int m0 = mt<<7, n0 = nt<<7;
  const int tid = threadIdx.x, wid = tid>>6, lane = tid&63, quad = lane>>4, tl = lane&15;
  const int mq = (wid&1)*64, nq = (wid>>1)*64;
  const int rowoff = wid*32 + (lane>>3);          // staging row of this lane
  const int cch    = (lane&7) ^ (lane>>3);        // pre-swizzled chunk index
  f4v acc[4][4];
#pragma unroll
  for(int i=0;i<4;i++)
#pragma unroll
    for(int j=0;j<4;j++) acc[i][j] = (f4v)(0.f);

  for(int kc=0; kc<KTOT; kc+=64){
    __syncthreads();
    const unsigned short* Ab = (MODE==0 && kc>=1024) ? A1 : A0;
    const int kb = (MODE==0) ? (kc & 1023) : kc;
    const unsigned short* ap = Ab + (size_t)(m0 + rowoff)*1024 + kb + cch*8;
    const unsigned short* bp = WT + (size_t)(n0 + rowoff)*KTOT + kc + cch*8;
#pragma unroll
    for(int i=0;i<4;i++){
      gl16(ap + (size_t)(i*8)*1024, &As[wid*2048 + i*512]);
      gl16(bp + (size_t)(i*8)*KTOT, &Bs[wid*2048 + i*512]);
    }
    __syncthreads();   // compiler drains vmcnt before s_barrier
#pragma unroll
    for(int ks=0; ks<2; ks++){
      s8v af[4], bf[4];
#pragma unroll
      for(int i=0;i<4;i++){
        int ml = mq + i*16 + tl;
        af[i] = *(const s8v*)&As[ml*64 + (((ks*4+quad) ^ (ml&7))<<3)];
      }
#pragma unroll
      for(int j=0;j<4;j++){
        int nl = nq + j*16 + tl;
        bf[j] = *(const s8v*)&Bs[nl*64 + (((ks*4+quad) ^ (nl&7))<<3)];
      }
#pragma unroll
      for(int i=0;i<4;i++)
#pragma unroll
        for(int j=0;j<4;j++)
          acc[i][j] = __builtin_amdgcn_mfma_f32_16x16x32_bf16(af[i], bf[j], acc[i][j], 0, 0, 0);
    }
  }

#pragma unroll
  for(int i=0;i<4;i++){
#pragma unroll
    for(int r=0;r<4;r++){
      int m = m0 + mq + i*16 + quad*4 + r;
      size_t rowb = (size_t)m * 1024;
#pragma unroll
      for(int j=0;j<4;j++){
        int nn = n0 + nq + j*16 + tl;
        float v = acc[i][j][r] + bias[nn];
        if(MODE==0){
          float g  = 1.0f/(1.0f + __expf(-v));
          float lv = f_lo((unsigned int)loc[rowb+nn]);
          float gv = f_lo((unsigned int)glo[rowb+nn]);
          float bv = f_lo((unsigned int)bcb[rowb+nn]);
          outb[rowb+nn] = f2bf(g*lv + (1.0f-g)*gv + bv);
        } else {
          outf[rowb+nn] = v;
        }
      }
    }
  }
}

extern "C" void kernel_launch(void* const* d_in, const int* in_sizes, int n_in,
                              void* d_out, int out_size, void* d_ws, size_t ws_size,
                              hipStream_t stream){
  const float* x  = (const float*)d_in[0];
  const float* gm = (const float*)d_in[1];
  const float* cw = (const float*)d_in[2];
  const float* cb = (const float*)d_in[3];
  const float* mw = (const float*)d_in[4];
  const float* mb = (const float*)d_in[5];
  const float* ow = (const float*)d_in[6];
  const float* ob = (const float*)d_in[7];
  float* out = (float*)d_out;

  char* ws = (char*)d_ws;
  const size_t SZ = (size_t)B_*S_*DM*2;                 // 16.78 MB per bf16 field
  unsigned short* localb = (unsigned short*)(ws);
  unsigned short* globb  = (unsigned short*)(ws + SZ);
  unsigned short* bcb    = (unsigned short*)(ws + 2*SZ);
  unsigned short* kvb    = (unsigned short*)(ws + 3*SZ);
  unsigned short* wso    = (unsigned short*)(ws + 3*SZ + 524288);
  unsigned short* mixed  = wso;                          // first 16.78 MB of wso region
  unsigned short* wt1    = (unsigned short*)(ws + 3*SZ + 524288 + SZ);            // 4 MB
  unsigned short* wt2    = (unsigned short*)(ws + 3*SZ + 524288 + SZ + 4194304);  // 2 MB
  // conv-path scratch overlays localb region (consumed before xbf is written)
  unsigned short* cwb    = (unsigned short*)(ws);               // 8 MB bf16 [1024][4096]
  unsigned short* asta   = (unsigned short*)(ws + 8388608);     // 1 MB bf16 [128][4096]
  float*          cpart  = (float*)        (ws + 9437184);      // 2 MB fp32 [4][128][1024]
  // overlays: xT over globb+bcb (dead until attn<1>/bcxpose); bcT over wso
  float*          xT     = (float*)(ws + SZ);                   // 33.5 MB fp32 [b][1024][4096]
  unsigned short* bcT    = wso;                                 // 16.78 MB bf16 [b][1024][4096]
  unsigned short* xbf    = (unsigned short*)(ws);               // 16.78 MB bf16 x (over conv scratch)

  // conv path (uses ws[0..11.5M]; must fully precede k_xposef's xbf write)
  k_cvtbf   <<<2048, 256, 0, stream>>>(cw, cwb);
  k_xstage  <<<128,  256, 0, stream>>>(x, asta);
  k_gemmconv<<<dim3(8,4), 256, 0, stream>>>(asta, cwb, cpart);
  k_convred <<<512,  256, 0, stream>>>(cpart, cb, kvb);
  k_gmem    <<<512,  256, 0, stream>>>(gm, kvb);
  // diffusion path (transposed space); xposef also emits bf16 x
  k_xposef  <<<2048, 256, 0, stream>>>(x, xT, xbf);
  k_diffuseT<<<1024, 256, 0, stream>>>(xT, bcT);
  k_bcxpose <<<2048, 256, 0, stream>>>(bcT, bcb);
  k_attn<1> <<<dim3(512,2), 256, 0, stream>>>(xbf, kvb, globb);
  k_attn<0> <<<dim3(960,2), 256, 0, stream>>>(xbf, kvb, wso);   // overwrites bcT (dead)
  k_combine <<<8192, 256, 0, stream>>>(wso, localb);            // overwrites xbf (dead)
  k_wcvt    <<<512,  256, 0, stream>>>(mw, wt1, 2048);
  k_wcvt    <<<256,  256, 0, stream>>>(ow, wt2, 1024);
  k_gemm2<0><<<512, 256, 0, stream>>>(localb, globb, wt1, mb, localb, globb, bcb, mixed, nullptr);
  k_gemm2<1><<<512, 256, 0, stream>>>(mixed, nullptr, wt2, ob, nullptr, nullptr, nullptr, nullptr, out);
}

// Round 8
// 352.010 us; speedup vs baseline: 1.5063x; 1.0402x over previous
//
#include <hip/hip_runtime.h>
#include <cstdint>

#define B_   2
#define S_   4096
#define DM   1024
#define NH   8
#define HDIM 128
#define NWIN 15

typedef __attribute__((ext_vector_type(8))) short s8v;   // 8 bf16 (4 VGPRs)
typedef __attribute__((ext_vector_type(4))) float f4v;   // 4 fp32 acc

__device__ __forceinline__ float f_lo(unsigned int u){
  union { unsigned int i; float f; } v; v.i = u << 16; return v.f;
}
__device__ __forceinline__ float f_hi(unsigned int u){
  union { unsigned int i; float f; } v; v.i = u & 0xffff0000u; return v.f;
}
__device__ __forceinline__ unsigned short f2bf(float f){
  unsigned int x = __float_as_uint(f);
  x += 0x7fffu + ((x >> 16) & 1u);
  return (unsigned short)(x >> 16);
}
__device__ __forceinline__ unsigned int pack2(float a, float b){
  return (unsigned int)f2bf(a) | ((unsigned int)f2bf(b) << 16);
}
// async global->LDS DMA, 16B per lane; LDS dest = wave-uniform base + lane*16
__device__ __forceinline__ void gl16(const unsigned short* g, unsigned short* l){
  __builtin_amdgcn_global_load_lds(
      (const __attribute__((address_space(1))) unsigned int*)g,
      (__attribute__((address_space(3))) unsigned int*)l, 16, 0, 0);
}

// ---------------------------------------------------------------------------
// R13: fused preprocessing (cw convert + conv A staging ONLY — weight
// transposes MUST run after k_combine: wt1/wt2 overlay wso's tail, which
// k_attn<0> writes.  R7's bug was moving them here.)
//   [0,2048)     : cw fp32 -> bf16 (cwb)
//   [2048,2176)  : xstage (conv A staging)
// ---------------------------------------------------------------------------
__global__ __launch_bounds__(256) void k_prep(const float* __restrict__ cw,
                                              unsigned short* __restrict__ cwb,
                                              const float* __restrict__ x,
                                              unsigned short* __restrict__ asta){
  __shared__ float smem[4096];
  const int bid = blockIdx.x;
  const int tid = threadIdx.x;
  if(bid < 2048){
    size_t i = ((size_t)bid*256 + tid)*8;
    float4 a = *(const float4*)(cw + i);
    float4 b = *(const float4*)(cw + i + 4);
    uint4 r; r.x = pack2(a.x,a.y); r.y = pack2(a.z,a.w);
    r.z = pack2(b.x,b.y); r.w = pack2(b.z,b.w);
    *(uint4*)(cwb + i) = r;
  } else {
    float (*xs)[1024] = (float(*)[1024])smem;
    const int m = bid - 2048;            // 0..127
    const int b = m>>6, t = m&63;
    const float* xp = x + (size_t)(b*S_ + 4*t)*DM;
    for(int i=tid; i<4096; i+=256) xs[i>>10][i&1023] = xp[i];
    __syncthreads();
    float v[16];
#pragma unroll
    for(int e=0; e<16; e++) v[e] = xs[e&3][tid*4 + (e>>2)];
    uint4 r0, r1;
    r0.x = pack2(v[0],v[1]);  r0.y = pack2(v[2],v[3]);
    r0.z = pack2(v[4],v[5]);  r0.w = pack2(v[6],v[7]);
    r1.x = pack2(v[8],v[9]);  r1.y = pack2(v[10],v[11]);
    r1.z = pack2(v[12],v[13]); r1.w = pack2(v[14],v[15]);
    unsigned short* op = asta + (size_t)m*4096 + tid*16;
    *(uint4*)op = r0;
    *(uint4*)(op+8) = r1;
  }
}

// ---------------------------------------------------------------------------
// Fused weight transpose+convert (mw->wt1, ow->wt2).  Runs AFTER k_combine
// (wt regions overlay wso's dead tail — ordering is load-bearing!).
//   [0,512)   : mw (K=2048), 32 kt x 16 nt
//   [512,768) : ow (K=1024), 16 kt x 16 nt
// ---------------------------------------------------------------------------
__global__ __launch_bounds__(256) void k_wcvt2(const float* __restrict__ mw,
                                               unsigned short* __restrict__ wt1,
                                               const float* __restrict__ ow,
                                               unsigned short* __restrict__ wt2){
  __shared__ float Ls[64][68];
  const int bid = blockIdx.x;
  const int tid = threadIdx.x;
  const float* W; unsigned short* WT; int K, r;
  if(bid < 512){ W = mw; WT = wt1; K = 2048; r = bid; }
  else         { W = ow; WT = wt2; K = 1024; r = bid - 512; }
  int kt = r >> 4, nt = r & 15;
  int k0 = kt<<6, n0 = nt<<6;
#pragma unroll
  for(int p=0; p<4; p++){
    int rr = p*16 + (tid>>4), c4 = (tid&15)*4;
    float4 v = *(const float4*)(W + (size_t)(k0+rr)*1024 + n0 + c4);
    *(float4*)&Ls[rr][c4] = v;
  }
  __syncthreads();
  int nn = tid>>2, kq = tid&3;
#pragma unroll
  for(int c=0; c<4; c++){
    int k = kq*16 + c*4;
    ushort4 u = { f2bf(Ls[k+0][nn]), f2bf(Ls[k+1][nn]), f2bf(Ls[k+2][nn]), f2bf(Ls[k+3][nn]) };
    *(ushort4*)(WT + (size_t)(n0+nn)*K + k0 + k) = u;
  }
}

// ---------------------------------------------------------------------------
// fp32 transpose: x [b][s][1024] -> xT [b][1024][s].  64x64 tiles.
// Also emits bf16 x (xbf) in the load phase.
// ---------------------------------------------------------------------------
__global__ __launch_bounds__(256) void k_xposef(const float* __restrict__ x,
                                                float* __restrict__ xT,
                                                unsigned short* __restrict__ xbf){
  __shared__ float Ls[64][68];
  const int bid = blockIdx.x;             // b*1024 + st*16 + dt
  const int b = bid>>10, r = bid&1023, st = r>>4, dt = r&15;
  const int s0 = st*64, d0 = dt*64;
  const int tid = threadIdx.x;
#pragma unroll
  for(int p=0;p<4;p++){
    int rr = p*16 + (tid>>4), c4 = (tid&15)*4;
    float4 v = *(const float4*)(x + ((size_t)(b*S_)+s0+rr)*DM + d0 + c4);
    *(float4*)&Ls[rr][c4] = v;
    ushort4 u = { f2bf(v.x), f2bf(v.y), f2bf(v.z), f2bf(v.w) };
    *(ushort4*)(xbf + ((size_t)(b*S_)+s0+rr)*DM + d0 + c4) = u;
  }
  __syncthreads();
#pragma unroll
  for(int p=0;p<4;p++){
    int dr = p*16 + (tid>>4), c4 = (tid&15)*4;
    float4 v = { Ls[c4+0][dr], Ls[c4+1][dr], Ls[c4+2][dr], Ls[c4+3][dr] };
    *(float4*)(xT + ((size_t)(b*DM)+d0+dr)*S_ + s0 + c4) = v;
  }
}

// ---------------------------------------------------------------------------
// Diffusion in transposed space; stages 8..11 in registers (R11).
// ---------------------------------------------------------------------------
__global__ __launch_bounds__(256) void k_diffuseT(const float* __restrict__ xT,
                                                  unsigned short* __restrict__ bcT){
  __shared__ float bufA[2][4096];
  __shared__ float bufB[2][4096];
  const int b  = blockIdx.x >> 9;
  const int d0 = (blockIdx.x & 511) * 2;
  const int tid = threadIdx.x;
  float curA_[32], curB_[32], res[32];
#pragma unroll
  for(int k=0;k<32;k++){
    int e = tid + (k<<8); int ch = e>>12; int s = e&4095;
    float v = xT[((size_t)(b*DM)+d0+ch)*S_ + s];
    curA_[k] = v; res[k] = 0.f; bufA[ch][s] = v;
  }
  __syncthreads();
#pragma unroll 1
  for(int st=0; st<8; st++){
    const int stride = 1<<st;
    float (*src)[4096] = (st&1) ? bufB : bufA;
    float (*dst)[4096] = (st&1) ? bufA : bufB;
#pragma unroll
    for(int k=0;k<32;k++){
      int e = tid + (k<<8); int ch=e>>12; int s=e&4095;
      float c = curA_[k] + 0.5f*(src[ch][(s-stride)&4095] + src[ch][(s+stride)&4095]);
      dst[ch][s] = c; curA_[k] = c; res[k] += c;
    }
    __syncthreads();
  }
  // stages 8..11 in registers: neighbor reg index = ch*16 + ((kk +- m)&15)
#pragma unroll
  for(int k=0;k<32;k++){
    int ch=k>>4, kk=k&15;
    curB_[k] = curA_[k] + 0.5f*(curA_[ch*16 + ((kk-1)&15)] + curA_[ch*16 + ((kk+1)&15)]);
    res[k] += curB_[k];
  }
#pragma unroll
  for(int k=0;k<32;k++){
    int ch=k>>4, kk=k&15;
    curA_[k] = curB_[k] + 0.5f*(curB_[ch*16 + ((kk-2)&15)] + curB_[ch*16 + ((kk+2)&15)]);
    res[k] += curA_[k];
  }
#pragma unroll
  for(int k=0;k<32;k++){
    int ch=k>>4, kk=k&15;
    curB_[k] = curA_[k] + 0.5f*(curA_[ch*16 + ((kk-4)&15)] + curA_[ch*16 + ((kk+4)&15)]);
    res[k] += curB_[k];
  }
#pragma unroll
  for(int k=0;k<32;k++){
    int ch=k>>4, kk=k&15;
    curA_[k] = curB_[k] + 0.5f*(curB_[ch*16 + ((kk-8)&15)] + curB_[ch*16 + ((kk+8)&15)]);
    res[k] += curA_[k];
  }
#pragma unroll
  for(int k=0;k<32;k++){
    int e = tid + (k<<8); int ch=e>>12; int s=e&4095;
    bcT[((size_t)(b*DM)+d0+ch)*S_ + s] = f2bf(res[k]*(1.0f/13.0f));
  }
}

// ---------------------------------------------------------------------------
// bf16 transpose back: bcT [b][1024][s] -> bc [b][s][1024]. 64x64 tiles.
// ---------------------------------------------------------------------------
__global__ __launch_bounds__(256) void k_bcxpose(const unsigned short* __restrict__ bcT,
                                                 unsigned short* __restrict__ bc){
  __shared__ unsigned short Ls[64*72];
  const int bid = blockIdx.x;             // b*1024 + st*16 + dt
  const int b = bid>>10, r = bid&1023, st = r>>4, dt = r&15;
  const int s0 = st*64, d0 = dt*64;
  const int tid = threadIdx.x;
#pragma unroll
  for(int t=0;t<2;t++){
    int cl = tid + t*256; int dr = cl>>3, c = cl&7;
    *(uint4*)&Ls[dr*72 + c*8] = *(const uint4*)(bcT + ((size_t)(b*DM)+d0+dr)*S_ + s0 + c*8);
  }
  __syncthreads();
#pragma unroll
  for(int t=0;t<2;t++){
    int cl = tid + t*256; int sr = cl>>3, c = cl&7;
    unsigned short tmp[8];
#pragma unroll
    for(int j=0;j<8;j++) tmp[j] = Ls[(c*8+j)*72 + sr];
    *(uint4*)(bc + ((size_t)(b*S_)+s0+sr)*DM + d0 + c*8) = *(const uint4*)tmp;
  }
}

// ---------------------------------------------------------------------------
// Conv GEMM. K-split 16 (grid 8 nt x 16 kt, 4 K-iters each).
// ---------------------------------------------------------------------------
__global__ __launch_bounds__(256) void k_gemmconv(const unsigned short* __restrict__ A,
                                                  const unsigned short* __restrict__ Bw,
                                                  float* __restrict__ part){
  __shared__ __align__(16) unsigned short As[128*64];
  __shared__ __align__(16) unsigned short Bs[128*64];
  const int nt = blockIdx.x, kt = blockIdx.y;
  const int n0 = nt<<7;
  const int tid = threadIdx.x, wid = tid>>6, lane = tid&63, quad = lane>>4, tl = lane&15;
  const int mq = (wid&1)*64, nq = (wid>>1)*64;
  f4v acc[4][4];
#pragma unroll
  for(int i=0;i<4;i++)
#pragma unroll
    for(int j=0;j<4;j++) acc[i][j] = (f4v)(0.f);

  for(int kc=kt*256; kc<kt*256+256; kc+=64){
    __syncthreads();
#pragma unroll
    for(int t=0; t<4; t++){
      int cl = tid + t*256, m = cl>>3, c = cl&7;
      uint4 v = *(const uint4*)(A + (size_t)m*4096 + kc + c*8);
      *(uint4*)&As[m*64 + ((c ^ (m&7))<<3)] = v;
      uint4 w = *(const uint4*)(Bw + (size_t)(n0+m)*4096 + kc + c*8);
      *(uint4*)&Bs[m*64 + ((c ^ (m&7))<<3)] = w;
    }
    __syncthreads();
#pragma unroll
    for(int ks=0; ks<2; ks++){
      s8v af[4], bf[4];
#pragma unroll
      for(int i=0;i<4;i++){
        int ml = mq + i*16 + tl;
        af[i] = *(const s8v*)&As[ml*64 + (((ks*4+quad) ^ (ml&7))<<3)];
      }
#pragma unroll
      for(int j=0;j<4;j++){
        int nl = nq + j*16 + tl;
        bf[j] = *(const s8v*)&Bs[nl*64 + (((ks*4+quad) ^ (nl&7))<<3)];
      }
#pragma unroll
      for(int i=0;i<4;i++)
#pragma unroll
        for(int j=0;j<4;j++)
          acc[i][j] = __builtin_amdgcn_mfma_f32_16x16x32_bf16(af[i], bf[j], acc[i][j], 0, 0, 0);
    }
  }
  float* pp = part + (size_t)kt*131072;
#pragma unroll
  for(int i=0;i<4;i++)
#pragma unroll
    for(int r=0;r<4;r++){
      int m = mq + i*16 + quad*4 + r;
#pragma unroll
      for(int j=0;j<4;j++){
        int n = n0 + nq + j*16 + tl;
        pp[m*1024 + n] = acc[i][j][r];
      }
    }
}

// ---------------------------------------------------------------------------
// Fused conv-reduce (16 partials) + global-memory KV fill.
// ---------------------------------------------------------------------------
__global__ __launch_bounds__(256) void k_convgm(const float* __restrict__ part,
                                                const float* __restrict__ cb,
                                                const float* __restrict__ g,
                                                unsigned short* __restrict__ kv){
  const int bid = blockIdx.x;
  if(bid < 512){
    int i = bid*256 + threadIdx.x;   // 131072
    int m = i>>10, o = i&1023;
    float v = cb[o];
#pragma unroll
    for(int j=0;j<16;j++) v += part[i + j*131072];
    int b = m>>6, t = m&63, h = o>>7, hd = o&127;
    kv[((size_t)(b*NH + h)*128 + t)*HDIM + hd] = f2bf(v);
  } else {
    int i = (bid-512)*256 + threadIdx.x;   // 131072 total
    int hd = i & 127, gt = (i>>7)&63, h = (i>>13)&7, b = i>>16;
    kv[((size_t)(b*NH + h)*128 + 64 + gt)*HDIM + hd] = f2bf(g[((size_t)(h*64 + gt))*HDIM + hd]);
  }
}

// ---------------------------------------------------------------------------
// MFMA flash attention — UNCHANGED from R5/R6 (verified 77 us).
// ---------------------------------------------------------------------------
template<int MODE>
__global__ __launch_bounds__(256, 4) void k_attn(const unsigned short* __restrict__ xb,
                                                 const unsigned short* __restrict__ kvb,
                                                 unsigned short* __restrict__ outb){
  __shared__ __align__(16) unsigned short sh[17408];  // 34.8 KB
  constexpr int KSo = 0;      // K-tile [64][128] swizzled  (16 KB)
  constexpr int PSo = 0;      // P [64][64] swizzled — overlays K (safe: bar3)
  constexpr int VTo = 8192;   // V^T [128][72]              (18 KB)

  const int b = blockIdx.y;
  int h, n, qt, nkt;
  if(MODE==0){
    int r = blockIdx.x;                  // 960 = 15n * 8h * 8qt
    int s = (r&7)*120 + (r>>3);          // bijective chunked XCD swizzle
    qt = s&7; h = (s>>3)&7; n = s>>6; nkt = 8;
  } else {
    int r = blockIdx.x;                  // 512 = 8h * 64qt
    int s = (r&7)*64 + (r>>3);
    qt = s&63; h = s>>6; n = 0; nkt = 2;
  }

  const int tid  = threadIdx.x;
  const int wid  = tid>>6, lane = tid&63, quad = lane>>4, tl = lane&15;
  const int sQ   = (MODE==0) ? (n*256 + qt*64) : (qt*64);

  // Q fragments: ONE 16-row group per wave (16 q rows x 128 hd)
  s8v qf[4];
  {
    int qr = sQ + wid*16 + tl;
    const unsigned short* qp = xb + ((size_t)(b*S_) + qr)*DM + h*HDIM;
#pragma unroll
    for(int ks=0; ks<4; ks++)
      qf[ks] = *(const s8v*)(qp + ks*32 + quad*8);
  }

  const unsigned short* kbase = (MODE==0)
      ? xb + ((size_t)(b*S_) + n*256)*DM + h*HDIM
      : kvb + (size_t)(b*NH+h)*128*HDIM;
  const int kstride = (MODE==0) ? DM : HDIM;
  const int mrow = (tid&15)*4;     // base t-row of this thread's 4 rows
  const int cg   = tid>>4;         // hd granule (8 ushorts), 0..15

  // prologue: prefetch tile 0 into registers
  uint4 rg[4];
#pragma unroll
  for(int j=0;j<4;j++)
    rg[j] = *(const uint4*)(kbase + (size_t)(mrow+j)*kstride + cg*8);

  f4v oacc[8];
#pragma unroll
  for(int ht=0; ht<8; ht++) oacc[ht] = (f4v)(0.f);
  float l_ = 0.f;

  const float SC2 = 0.12751743f;   // (1/sqrt(128)) * log2(e)

  for(int kt=0; kt<nkt; kt++){
    __syncthreads();               // prev PV done reading P(=K region) and VT
    // --- stage K tile (swizzled) from regs: 4 conflict-free uint4 writes
#pragma unroll
    for(int j=0;j<4;j++){
      int t = mrow + j;
      *(uint4*)&sh[KSo + t*128 + ((cg ^ (t&7))<<3)] = rg[j];
    }
    // --- stage V^T from regs: pack 4 consecutive t per hd, ds_write_b64
    {
      const unsigned int* w0 = (const unsigned int*)&rg[0];
      const unsigned int* w1 = (const unsigned int*)&rg[1];
      const unsigned int* w2 = (const unsigned int*)&rg[2];
      const unsigned int* w3 = (const unsigned int*)&rg[3];
#pragma unroll
      for(int i=0;i<8;i++){
        int w = i>>1;
        unsigned int a, c2;
        if(i&1){ a  = (w0[w]>>16) | (w1[w] & 0xffff0000u);
                 c2 = (w2[w]>>16) | (w3[w] & 0xffff0000u); }
        else   { a  = (w0[w] & 0xffffu) | (w1[w]<<16);
                 c2 = (w2[w] & 0xffffu) | (w3[w]<<16); }
        uint2 u = {a, c2};
        *(uint2*)&sh[VTo + (cg*8+i)*72 + mrow] = u;
      }
    }
    __syncthreads();               // staging visible
    // --- prefetch next K tile into regs (latency hides under compute)
    if(kt+1 < nkt){
      const unsigned short* np = kbase + (size_t)((kt+1)*64 + mrow)*kstride + cg*8;
#pragma unroll
      for(int j=0;j<4;j++) rg[j] = *(const uint4*)(np + (size_t)j*kstride);
    }

    // --- S^T[t][q] = K.Q^T (raw scores, scale folded into exp2)
    f4v st[4];
    __builtin_amdgcn_s_setprio(1);
#pragma unroll
    for(int tt=0; tt<4; tt++){
      st[tt] = (f4v)(0.f);
      int row = tt*16 + tl;
#pragma unroll
      for(int ks=0; ks<4; ks++){
        s8v af = *(const s8v*)&sh[KSo + row*128 + (((ks*4+quad) ^ (row&7))<<3)];
        st[tt] = __builtin_amdgcn_mfma_f32_16x16x32_bf16(af, qf[ks], st[tt], 0, 0, 0);
      }
    }
    __builtin_amdgcn_s_setprio(0);

    // --- softmax, no max subtraction (scores bounded; exp2 arg <= ~27)
    {
      float ps = 0.f;
#pragma unroll
      for(int tt=0; tt<4; tt++)
#pragma unroll
        for(int r=0; r<4; r++){
          float p = exp2f(st[tt][r]*SC2);
          st[tt][r] = p; ps += p;
        }
      ps += __shfl_xor(ps, 16);
      ps += __shfl_xor(ps, 32);
      l_ += ps;
    }

    __syncthreads();               // all waves' QK reads of K done -> P may overlay

    // --- P store: [64][64] XOR-swizzled (granule-8)
    {
      int ql = wid*16 + tl;
#pragma unroll
      for(int tt=0; tt<4; tt++){
        ushort4 u = { f2bf(st[tt][0]), f2bf(st[tt][1]),
                      f2bf(st[tt][2]), f2bf(st[tt][3]) };
        *(ushort4*)&sh[PSo + ql*64 + (((tt*2 + (quad>>1)) ^ (ql&7))<<3) + (quad&1)*4] = u;
      }
    }

    // --- O^T += V^T . P^T  (P rows are wave-private: no barrier needed)
    __builtin_amdgcn_s_setprio(1);
#pragma unroll
    for(int kk=0; kk<2; kk++){
      int ql = wid*16 + tl;
      s8v pb = *(const s8v*)&sh[PSo + ql*64 + (((kk*4+quad) ^ (ql&7))<<3)];
#pragma unroll
      for(int ht=0; ht<8; ht++){
        s8v vf = *(const s8v*)&sh[VTo + (ht*16 + tl)*72 + kk*32 + quad*8];
        oacc[ht] = __builtin_amdgcn_mfma_f32_16x16x32_bf16(vf, pb, oacc[ht], 0, 0, 0);
      }
    }
    __builtin_amdgcn_s_setprio(0);
  }

  // normalize and write out via LDS transpose (64 rows x 136 stride)
  {
    float inv = 1.0f/l_;
#pragma unroll
    for(int ht=0; ht<8; ht++) oacc[ht] *= inv;
  }
  __syncthreads();
  {
    int ql = wid*16 + tl;
#pragma unroll
    for(int ht=0; ht<8; ht++){
      ushort4 u = { f2bf(oacc[ht][0]), f2bf(oacc[ht][1]),
                    f2bf(oacc[ht][2]), f2bf(oacc[ht][3]) };
      *(ushort4*)&sh[ql*136 + ht*16 + quad*4] = u;
    }
  }
  __syncthreads();
  {
    int ql = tid>>2, qu = tid&3;     // 64 rows x 4 quarters
    size_t row = (MODE==0) ? (size_t)((b*NWIN + n)*512 + qt*64 + ql)
                           : (size_t)(b*S_ + qt*64 + ql);
    unsigned short* op = outb + row*DM + h*HDIM + qu*32;
#pragma unroll
    for(int c=0; c<4; c++){
      uint4 v = *(const uint4*)&sh[ql*136 + qu*32 + c*8];
      *(uint4*)(op + c*8) = v;
    }
  }
}

// ---------------------------------------------------------------------------
// Triangular-weighted overlap-add
// ---------------------------------------------------------------------------
__global__ __launch_bounds__(256) void k_combine(const unsigned short* __restrict__ wso,
                                                 unsigned short* __restrict__ loc){
  const int bid = blockIdx.x;          // B*S
  const int b = bid >> 12, s = bid & 4095;
  const int tid = threadIdx.x;
  const int nhi = s >> 8, sl = s & 255;
  const int c0 = tid*4;
  float n0=0.f, n1=0.f, n2=0.f, n3=0.f, den=0.f;
  if(nhi <= 14){
    float tr = 0.5f + (float)sl*(1.0f/511.0f);
    den += tr;
    uint2 u = *(const uint2*)(wso + (size_t)((b*NWIN + nhi)*512 + sl)*DM + c0);
    n0 += tr*f_lo(u.x); n1 += tr*f_hi(u.x); n2 += tr*f_lo(u.y); n3 += tr*f_hi(u.y);
  }
  if(nhi >= 1){
    int q2 = sl + 256;
    float tr = 0.5f + (float)q2*(1.0f/511.0f);
    den += tr;
    uint2 u = *(const uint2*)(wso + (size_t)((b*NWIN + nhi-1)*512 + q2)*DM + c0);
    n0 += tr*f_lo(u.x); n1 += tr*f_hi(u.x); n2 += tr*f_lo(u.y); n3 += tr*f_hi(u.y);
  }
  float di = 1.0f/den;
  uint2 o; o.x = pack2(n0*di, n1*di); o.y = pack2(n2*di, n3*di);
  *(uint2*)(loc + (size_t)(b*S_ + s)*DM + c0) = o;
}

// ---------------------------------------------------------------------------
// MFMA GEMM 128x128 tile, BK=64, DMA staging (pre-swizzled source, R11).
// MODE 0: + sigmoid gate mix epilogue -> mixed (bf16).  MODE 1: + bias -> out fp32.
// ---------------------------------------------------------------------------
template<int MODE>
__global__ __launch_bounds__(256, 3) void k_gemm2(const unsigned short* __restrict__ A0,
                                               const unsigned short* __restrict__ A1,
                                               const unsigned short* __restrict__ WT,
                                               const float* __restrict__ bias,
                                               const unsigned short* __restrict__ loc,
                                               const unsigned short* __restrict__ glo,
                                               const unsigned short* __restrict__ bcb,
                                               unsigned short* __restrict__ outb,
                                               float* __restrict__ outf){
  const int KTOT = (MODE==0) ? 2048 : 1024;
  __shared__ __align__(16) unsigned short As[128*64];
  __shared__ __align__(16) unsigned short Bs[128*64];
  const int mt = blockIdx.x >> 3, nt = blockIdx.x & 7;
  const int m0 = mt<<7, n0 = nt<<7;
  const int tid = threadIdx.x, wid = tid>>6, lane = tid&63, quad = lane>>4, tl = lane&15;
  const int mq = (wid&1)*64, nq = (wid>>1)*64;
  const int rowoff = wid*32 + (lane>>3);          // staging row of this lane
  const int cch    = (lane&7) ^ (lane>>3);        // pre-swizzled chunk index
  f4v acc[4][4];
#pragma unroll
  for(int i=0;i<4;i++)
#pragma unroll
    for(int j=0;j<4;j++) acc[i][j] = (f4v)(0.f);

  for(int kc=0; kc<KTOT; kc+=64){
    __syncthreads();
    const unsigned short* Ab = (MODE==0 && kc>=1024) ? A1 : A0;
    const int kb = (MODE==0) ? (kc & 1023) : kc;
    const unsigned short* ap = Ab + (size_t)(m0 + rowoff)*1024 + kb + cch*8;
    const unsigned short* bp = WT + (size_t)(n0 + rowoff)*KTOT + kc + cch*8;
#pragma unroll
    for(int i=0;i<4;i++){
      gl16(ap + (size_t)(i*8)*1024, &As[wid*2048 + i*512]);
      gl16(bp + (size_t)(i*8)*KTOT, &Bs[wid*2048 + i*512]);
    }
    __syncthreads();   // compiler drains vmcnt before s_barrier
#pragma unroll
    for(int ks=0; ks<2; ks++){
      s8v af[4], bf[4];
#pragma unroll
      for(int i=0;i<4;i++){
        int ml = mq + i*16 + tl;
        af[i] = *(const s8v*)&As[ml*64 + (((ks*4+quad) ^ (ml&7))<<3)];
      }
#pragma unroll
      for(int j=0;j<4;j++){
        int nl = nq + j*16 + tl;
        bf[j] = *(const s8v*)&Bs[nl*64 + (((ks*4+quad) ^ (nl&7))<<3)];
      }
#pragma unroll
      for(int i=0;i<4;i++)
#pragma unroll
        for(int j=0;j<4;j++)
          acc[i][j] = __builtin_amdgcn_mfma_f32_16x16x32_bf16(af[i], bf[j], acc[i][j], 0, 0, 0);
    }
  }

#pragma unroll
  for(int i=0;i<4;i++){
#pragma unroll
    for(int r=0;r<4;r++){
      int m = m0 + mq + i*16 + quad*4 + r;
      size_t rowb = (size_t)m * 1024;
#pragma unroll
      for(int j=0;j<4;j++){
        int nn = n0 + nq + j*16 + tl;
        float v = acc[i][j][r] + bias[nn];
        if(MODE==0){
          float g  = 1.0f/(1.0f + __expf(-v));
          float lv = f_lo((unsigned int)loc[rowb+nn]);
          float gv = f_lo((unsigned int)glo[rowb+nn]);
          float bv = f_lo((unsigned int)bcb[rowb+nn]);
          outb[rowb+nn] = f2bf(g*lv + (1.0f-g)*gv + bv);
        } else {
          outf[rowb+nn] = v;
        }
      }
    }
  }
}

extern "C" void kernel_launch(void* const* d_in, const int* in_sizes, int n_in,
                              void* d_out, int out_size, void* d_ws, size_t ws_size,
                              hipStream_t stream){
  const float* x  = (const float*)d_in[0];
  const float* gm = (const float*)d_in[1];
  const float* cw = (const float*)d_in[2];
  const float* cb = (const float*)d_in[3];
  const float* mw = (const float*)d_in[4];
  const float* mb = (const float*)d_in[5];
  const float* ow = (const float*)d_in[6];
  const float* ob = (const float*)d_in[7];
  float* out = (float*)d_out;

  char* ws = (char*)d_ws;
  const size_t SZ = (size_t)B_*S_*DM*2;                 // 16.78 MB per bf16 field
  unsigned short* localb = (unsigned short*)(ws);
  unsigned short* globb  = (unsigned short*)(ws + SZ);
  unsigned short* bcb    = (unsigned short*)(ws + 2*SZ);
  unsigned short* kvb    = (unsigned short*)(ws + 3*SZ);
  unsigned short* wso    = (unsigned short*)(ws + 3*SZ + 524288);
  unsigned short* mixed  = wso;                          // first 16.78 MB of wso region
  unsigned short* wt1    = (unsigned short*)(ws + 3*SZ + 524288 + SZ);            // 4 MB
  unsigned short* wt2    = (unsigned short*)(ws + 3*SZ + 524288 + SZ + 4194304);  // 2 MB
  //   wt1/wt2 overlay wso's TAIL (wso spans 31.4MB) — k_wcvt2 must run after
  //   k_combine has consumed wso.  (R7 bug: running it first got clobbered.)
  // conv-path scratch overlays localb region (consumed before xbf is written)
  unsigned short* cwb    = (unsigned short*)(ws);               // 8 MB bf16 [1024][4096]
  unsigned short* asta   = (unsigned short*)(ws + 8388608);     // 1 MB bf16 [128][4096]
  float*          cpart  = (float*)        (ws + 9437184);      // 8 MB fp32 [16][128][1024]
  //   cpart extends to 17.8 MB — overlaps xT's first MB, but is consumed by
  //   k_convgm BEFORE k_xposef writes xT (stream-ordered).
  // overlays: xT over globb+bcb (dead until attn<1>/bcxpose); bcT over wso
  float*          xT     = (float*)(ws + SZ);                   // 33.5 MB fp32 [b][1024][4096]
  unsigned short* bcT    = wso;                                 // 16.78 MB bf16 [b][1024][4096]
  unsigned short* xbf    = (unsigned short*)(ws);               // 16.78 MB bf16 x (over conv scratch)

  // fused preprocessing: cw->bf16 + conv A staging
  k_prep    <<<2176, 256, 0, stream>>>(cw, cwb, x, asta);
  k_gemmconv<<<dim3(8,16), 256, 0, stream>>>(asta, cwb, cpart);
  k_convgm  <<<1024, 256, 0, stream>>>(cpart, cb, gm, kvb);
  // diffusion path (transposed space); xposef also emits bf16 x
  k_xposef  <<<2048, 256, 0, stream>>>(x, xT, xbf);
  k_diffuseT<<<1024, 256, 0, stream>>>(xT, bcT);
  k_bcxpose <<<2048, 256, 0, stream>>>(bcT, bcb);
  k_attn<1> <<<dim3(512,2), 256, 0, stream>>>(xbf, kvb, globb);
  k_attn<0> <<<dim3(960,2), 256, 0, stream>>>(xbf, kvb, wso);   // overwrites bcT (dead)
  k_combine <<<8192, 256, 0, stream>>>(wso, localb);            // overwrites xbf (dead)
  k_wcvt2   <<<768,  256, 0, stream>>>(mw, wt1, ow, wt2);       // AFTER combine (wso tail dead)
  k_gemm2<0><<<512, 256, 0, stream>>>(localb, globb, wt1, mb, localb, globb, bcb, mixed, nullptr);
  k_gemm2<1><<<512, 256, 0, stream>>>(mixed, nullptr, wt2, ob, nullptr, nullptr, nullptr, nullptr, out);
}